// Round 4
// baseline (418.440 us; speedup 1.0000x reference)
//
#include <hip/hip_runtime.h>

#define DEV static __device__ __forceinline__

typedef unsigned short u16;
typedef short bf16x8 __attribute__((ext_vector_type(8)));
typedef u16 u16x8v __attribute__((ext_vector_type(8)));
typedef u16 u16x4v __attribute__((ext_vector_type(4)));
typedef float f32x4 __attribute__((ext_vector_type(4)));

static constexpr int NB = 4, L = 1024, D = 512, H = 8, DH = 64;
static constexpr size_t E  = (size_t)NB * L * D;   // 2,097,152
static constexpr size_t WE = (size_t)D * D;        // 262,144

// d_ws layout in u16 units
static constexpr size_t OFF_X1H = 0;
static constexpr size_t OFF_X1L = OFF_X1H + E;
static constexpr size_t OFF_X2H = OFF_X1L + E;
static constexpr size_t OFF_X2L = OFF_X2H + E;
static constexpr size_t OFF_WH  = OFF_X2L + E;       // 6 x WE
static constexpr size_t OFF_WL  = OFF_WH + 6 * WE;   // 6 x WE
static constexpr size_t OFF_QKV = OFF_WL + 6 * WE;
// OFF_QKV + {0:q1h,1E:q1l,2E:k1h,3E:k1l,4E:q2h,5E:q2l,6E:k2h,7E:k2l,8E:v1t,9E:v2t}
// K stored dh-SWIZZLED (dh ^= (key&7)<<3); V^T stored key-SWIZZLED
// (key ^= (dh&7)<<3 within each 64-key tile) so linear global_load_lds staging
// yields bank-conflict-free ds_read_b128 fragments (rule #21).
static constexpr size_t OFF_VLEN = OFF_QKV + 10 * E; // int[8] (s*4+n)

DEV u16 f2bf(float x) {
    unsigned u = __builtin_bit_cast(unsigned, x);
    unsigned r = u + 0x7FFFu + ((u >> 16) & 1u);
    return (u16)(r >> 16);
}
DEV float bf2f(u16 h) {
    unsigned u = ((unsigned)h) << 16;
    return __builtin_bit_cast(float, u);
}
DEV bf16x8 ldfrag(const u16* p) {
    u16x8v t = *reinterpret_cast<const u16x8v*>(p);
    return __builtin_bit_cast(bf16x8, t);
}
typedef __attribute__((address_space(1))) const unsigned gas_u32;
typedef __attribute__((address_space(3))) unsigned las_u32;
DEV void gld16(const u16* g, u16* l) {
    __builtin_amdgcn_global_load_lds((gas_u32*)g, (las_u32*)l, 16, 0, 0);
}

// ---------------- fused split fp32 -> (hi, lo) bf16 for X1, X2, W0..W5 ----------------
// blocks: [0,2048) X1, [2048,4096) X2, [4096,5632) weights (256 blocks each)
__global__ __launch_bounds__(256) void k_split_all(const float* __restrict__ x1,
                                                   const float* __restrict__ x2,
                                                   const float* w0, const float* w1,
                                                   const float* w2, const float* w3,
                                                   const float* w4, const float* w5,
                                                   u16* __restrict__ ws) {
    int b = blockIdx.x;
    const float* src;
    u16 *hi, *lo;
    int i0;
    if (b < 2048)      { src = x1; hi = ws + OFF_X1H; lo = ws + OFF_X1L; i0 = b; }
    else if (b < 4096) { src = x2; hi = ws + OFF_X2H; lo = ws + OFF_X2L; i0 = b - 2048; }
    else {
        int wi = (b - 4096) >> 8;
        const float* wp[6] = {w0, w1, w2, w3, w4, w5};
        src = wp[wi];
        hi = ws + OFF_WH + (size_t)wi * WE;
        lo = ws + OFF_WL + (size_t)wi * WE;
        i0 = (b - 4096) & 255;
    }
    int i = i0 * 256 + threadIdx.x;
    float4 v = reinterpret_cast<const float4*>(src)[i];
    float xs[4] = {v.x, v.y, v.z, v.w};
    u16x4v h, l;
#pragma unroll
    for (int j = 0; j < 4; j++) {
        u16 hh = f2bf(xs[j]);
        h[j] = hh;
        l[j] = f2bf(xs[j] - bf2f(hh));
    }
    reinterpret_cast<u16x4v*>(hi)[i] = h;
    reinterpret_cast<u16x4v*>(lo)[i] = l;
}

// ---------------- valid-length per (src, n): prefix-mask sum ----------------
__global__ __launch_bounds__(256) void k_vlen(const float* __restrict__ m1,
                                              const float* __restrict__ m2,
                                              int* __restrict__ vl) {
    int b = blockIdx.x;            // 0..7 : s*4+n
    int s = b >> 2, n = b & 3;
    const float* m = (s ? m2 : m1) + n * L;
    float p = 0.f;
    for (int i = threadIdx.x; i < L; i += 256) p += m[i];
#pragma unroll
    for (int mk = 1; mk < 64; mk <<= 1) p += __shfl_xor(p, mk, 64);
    __shared__ float w4[4];
    if ((threadIdx.x & 63) == 0) w4[threadIdx.x >> 6] = p;
    __syncthreads();
    if (threadIdx.x == 0) vl[b] = (int)(w4[0] + w4[1] + w4[2] + w4[3] + 0.5f);
}

// ---------------- projections, 128x64 block tile, 32 rows/wave ----------------
__global__ __launch_bounds__(256) void k_proj(u16* __restrict__ ws) {
    const int b     = blockIdx.x;
    const int proj  = b >> 8;        // 0..5 : q1,k1,v1,q2,k2,v2
    const int rem   = b & 255;
    const int mtile = rem >> 3;
    const int ntile = rem & 7;
    const int tid   = threadIdx.x;
    const int w     = tid >> 6;
    const int lane  = tid & 63;
    const int lr    = lane & 15;
    const int g     = lane >> 4;

    const int src  = proj / 3;
    const int kind = proj % 3;
    const u16* Xh = ws + (src ? OFF_X2H : OFF_X1H);
    const u16* Xl = ws + (src ? OFF_X2L : OFF_X1L);
    const u16* Wh = ws + OFF_WH + (size_t)proj * WE;
    const u16* Wl = ws + OFF_WL + (size_t)proj * WE;

    const int m0 = mtile * 128 + w * 32;
    const int n0 = ntile * 64;

    f32x4 acc[2][4];
#pragma unroll
    for (int rb = 0; rb < 2; rb++)
#pragma unroll
        for (int cb = 0; cb < 4; cb++) acc[rb][cb] = {0.f, 0.f, 0.f, 0.f};

    const u16* xh0 = Xh + (size_t)(m0 + lr) * D + g * 8;
    const u16* xh1 = Xh + (size_t)(m0 + 16 + lr) * D + g * 8;
    const u16* xl0 = Xl + (size_t)(m0 + lr) * D + g * 8;
    const u16* xl1 = Xl + (size_t)(m0 + 16 + lr) * D + g * 8;
#pragma unroll 4
    for (int e = 0; e < D; e += 32) {
        bf16x8 ah0 = ldfrag(xh0 + e), ah1 = ldfrag(xh1 + e);
        bf16x8 al0 = ldfrag(xl0 + e), al1 = ldfrag(xl1 + e);
#pragma unroll
        for (int cb = 0; cb < 4; cb++) {
            const u16* pwh = Wh + (size_t)(n0 + cb * 16 + lr) * D + e + g * 8;
            const u16* pwl = Wl + (size_t)(n0 + cb * 16 + lr) * D + e + g * 8;
            bf16x8 bh = ldfrag(pwh);
            bf16x8 bl = ldfrag(pwl);
            acc[0][cb] = __builtin_amdgcn_mfma_f32_16x16x32_bf16(ah0, bh, acc[0][cb], 0, 0, 0);
            acc[0][cb] = __builtin_amdgcn_mfma_f32_16x16x32_bf16(ah0, bl, acc[0][cb], 0, 0, 0);
            acc[0][cb] = __builtin_amdgcn_mfma_f32_16x16x32_bf16(al0, bh, acc[0][cb], 0, 0, 0);
            acc[1][cb] = __builtin_amdgcn_mfma_f32_16x16x32_bf16(ah1, bh, acc[1][cb], 0, 0, 0);
            acc[1][cb] = __builtin_amdgcn_mfma_f32_16x16x32_bf16(ah1, bl, acc[1][cb], 0, 0, 0);
            acc[1][cb] = __builtin_amdgcn_mfma_f32_16x16x32_bf16(al1, bh, acc[1][cb], 0, 0, 0);
        }
    }

    if (kind < 2) {
        u16* dhi = ws + OFF_QKV + (size_t)(src * 4 + kind * 2) * E;
        u16* dlo = dhi + E;
#pragma unroll
        for (int rb = 0; rb < 2; rb++)
#pragma unroll
            for (int cb = 0; cb < 4; cb++) {
                int d  = n0 + cb * 16 + lr;
                int hh = d >> 6, dh = d & 63;
#pragma unroll
                for (int r = 0; r < 4; r++) {
                    int m = m0 + rb * 16 + g * 4 + r;
                    int n = m >> 10, li = m & 1023;
                    int dhs = kind ? (dh ^ ((li & 7) << 3)) : dh;   // K dh-swizzle
                    size_t idx = ((size_t)(n * H + hh) * L + li) * DH + dhs;
                    float v = acc[rb][cb][r];
                    u16 hv = f2bf(v);
                    dhi[idx] = hv;
                    dlo[idx] = f2bf(v - bf2f(hv));
                }
            }
    } else {
        u16* vt = ws + OFF_QKV + (size_t)(8 + src) * E;
#pragma unroll
        for (int rb = 0; rb < 2; rb++)
#pragma unroll
            for (int cb = 0; cb < 4; cb++) {
                int d  = n0 + cb * 16 + lr;
                int hh = d >> 6, dh = d & 63;
                int m  = m0 + rb * 16 + g * 4;
                int n  = m >> 10, li = m & 1023;
                int lis = li ^ ((dh & 7) << 3);   // V key-swizzle
                u16x4v pk;
#pragma unroll
                for (int r = 0; r < 4; r++) pk[r] = f2bf(acc[rb][cb][r]);
                *reinterpret_cast<u16x4v*>(vt + ((size_t)(n * H + hh) * DH + dh) * L + lis) = pk;
            }
    }
}

// ---------------- fused two-source, two-query flash attention ----------------
// grid: 4 n x 8 h x 16 qtiles = 512 blocks of 512 threads.
// wave w: oi = w>>2 (query source), s = (w>>1)&1 (key source), wq = w&1.
// Each wave owns 32 q-rows. K/V staged ONCE per block per kt, shared by all 8 waves.
__global__ __launch_bounds__(512, 4) void k_attn(const u16* __restrict__ ws,
                                                 const float* __restrict__ mask1,
                                                 const float* __restrict__ mask2,
                                                 float* __restrict__ out) {
    __shared__ __align__(16) u16 kbuf[2][2][64][64];  // [src][hi/lo][key][dh-swz] 32KB
    __shared__ __align__(16) u16 vbuf[2][64][64];     // [src][dh][key-swz]        16KB
    __shared__ __align__(16) u16 plds[8][32][64];     // per-wave P, XOR-swizzled  32KB

    const int b    = blockIdx.x;
    const int qt   = b & 15;
    const int hh   = (b >> 4) & 7;
    const int n    = b >> 7;
    const int tid  = threadIdx.x;
    const int w    = tid >> 6;
    const int oi   = w >> 2;
    const int s    = (w >> 1) & 1;
    const int wq   = w & 1;
    const int lane = tid & 63;
    const int lr   = lane & 15;
    const int g    = lane >> 4;

    const size_t nh = (size_t)(n * H + hh);
    const u16* Qh = ws + OFF_QKV + (size_t)(oi * 4) * E;
    const u16* Ql = Qh + E;
    const float* maskrow = oi ? mask2 : mask1;
    const float* maskc   = s  ? mask2 : mask1;
    const int* vl = (const int*)(ws + OFF_VLEN);

    const int l0 = qt * 64 + wq * 32;
    bf16x8 qh[2][2], ql[2][2];
#pragma unroll
    for (int rt = 0; rt < 2; rt++) {
        const size_t qb = (nh * L + l0 + rt * 16 + lr) * DH + g * 8;
        qh[rt][0] = ldfrag(Qh + qb);      qh[rt][1] = ldfrag(Qh + qb + 32);
        ql[rt][0] = ldfrag(Ql + qb);      ql[rt][1] = ldfrag(Ql + qb + 32);
    }

    float mrun[8], lrun[8];
    f32x4 oacc[8];
#pragma unroll
    for (int r = 0; r < 8; r++) { mrun[r] = -1e30f; lrun[r] = 0.f; }
#pragma unroll
    for (int d = 0; d < 8; d++) oacc[d] = {0.f, 0.f, 0.f, 0.f};

    const int nkt0 = (vl[n] + 63) >> 6;
    const int nkt1 = (vl[4 + n] + 63) >> 6;
    const int mykt = s ? nkt1 : nkt0;
    const int nktmax = nkt0 > nkt1 ? nkt0 : nkt1;

    // staging: 48 x 1KB chunks per kt, 6 per wave; pointers hoisted out of loop.
    const int lane8 = lane >> 3, lanec = lane & 7;
    const u16* gsrc[6];
    u16* ldst[6];
    int ginc[6];
#pragma unroll
    for (int i = 0; i < 6; i++) {
        const int c  = w * 6 + i;
        const int cs = c / 24, cr = c % 24;
        if (cr < 16) {
            const int hl = cr >> 3, rr = cr & 7;
            const u16* K = ws + OFF_QKV + (size_t)(2 + cs * 4 + hl) * E;
            gsrc[i] = K + (nh * L + rr * 8 + lane8) * DH + lanec * 8;
            ldst[i] = &kbuf[cs][hl][rr * 8][0];
            ginc[i] = 64 * DH;            // next key tile
        } else {
            const int rr = cr - 16;
            const u16* V = ws + OFF_QKV + (size_t)(8 + cs) * E;
            gsrc[i] = V + (nh * DH + rr * 8 + lane8) * L + lanec * 8;
            ldst[i] = &vbuf[cs][rr * 8][0];
            ginc[i] = 64;                 // next key tile (key is inner dim)
        }
    }

#pragma unroll 1
    for (int kt = 0; kt < nktmax; kt++) {
        __syncthreads();   // previous tile's compute done
#pragma unroll
        for (int i = 0; i < 6; i++) {
            gld16(gsrc[i], ldst[i]);
            gsrc[i] += ginc[i];
        }
        __syncthreads();   // staged data visible

        if (kt < mykt) {
            // mask subtraction values for this tile (shared by both row-tiles)
            float msub[4];
#pragma unroll
            for (int j = 0; j < 4; j++)
                msub[j] = (maskc[n * L + kt * 64 + j * 16 + lr] > 0.f) ? 0.f : 10000.f;

#pragma unroll
            for (int rt = 0; rt < 2; rt++) {
                f32x4 sfr[4];
#pragma unroll
                for (int j = 0; j < 4; j++) {
                    const int row = j * 16 + lr;
                    const int t0 = g ^ (row & 7);
                    const int t1 = (g + 4) ^ (row & 7);
                    bf16x8 kh0 = ldfrag(&kbuf[s][0][row][t0 * 8]);
                    bf16x8 kh1 = ldfrag(&kbuf[s][0][row][t1 * 8]);
                    bf16x8 kl0 = ldfrag(&kbuf[s][1][row][t0 * 8]);
                    bf16x8 kl1 = ldfrag(&kbuf[s][1][row][t1 * 8]);
                    f32x4 a = {0.f, 0.f, 0.f, 0.f};
                    a = __builtin_amdgcn_mfma_f32_16x16x32_bf16(qh[rt][0], kh0, a, 0, 0, 0);
                    a = __builtin_amdgcn_mfma_f32_16x16x32_bf16(qh[rt][1], kh1, a, 0, 0, 0);
                    a = __builtin_amdgcn_mfma_f32_16x16x32_bf16(qh[rt][0], kl0, a, 0, 0, 0);
                    a = __builtin_amdgcn_mfma_f32_16x16x32_bf16(qh[rt][1], kl1, a, 0, 0, 0);
                    a = __builtin_amdgcn_mfma_f32_16x16x32_bf16(ql[rt][0], kh0, a, 0, 0, 0);
                    a = __builtin_amdgcn_mfma_f32_16x16x32_bf16(ql[rt][1], kh1, a, 0, 0, 0);
                    a[0] -= msub[j]; a[1] -= msub[j]; a[2] -= msub[j]; a[3] -= msub[j];
                    sfr[j] = a;
                }
                // online softmax, rows rt*16 + g*4 + r
#pragma unroll
                for (int r = 0; r < 4; r++) {
                    const int ri = rt * 4 + r;
                    float tm = fmaxf(fmaxf(sfr[0][r], sfr[1][r]), fmaxf(sfr[2][r], sfr[3][r]));
#pragma unroll
                    for (int mk = 1; mk < 16; mk <<= 1) tm = fmaxf(tm, __shfl_xor(tm, mk, 64));
                    float mnew = fmaxf(mrun[ri], tm);
                    float sc = __expf(mrun[ri] - mnew);
                    float ps = 0.f;
                    const int row = g * 4 + r;
#pragma unroll
                    for (int j = 0; j < 4; j++) {
                        float p = __expf(sfr[j][r] - mnew);
                        ps += p;
                        plds[w][rt * 16 + row][(j * 16 + lr) ^ ((row & 7) << 3)] = f2bf(p);
                    }
#pragma unroll
                    for (int mk = 1; mk < 16; mk <<= 1) ps += __shfl_xor(ps, mk, 64);
                    mrun[ri] = mnew;
                    lrun[ri] = lrun[ri] * sc + ps;
#pragma unroll
                    for (int d = 0; d < 4; d++) oacc[rt * 4 + d][r] *= sc;
                }
                // P fragments and PV
                bf16x8 pa[2];
#pragma unroll
                for (int ks = 0; ks < 2; ks++) {
                    int base = (ks * 32 + g * 8) ^ ((lr & 7) << 3);
                    u16x8v t = *reinterpret_cast<const u16x8v*>(&plds[w][rt * 16 + lr][base]);
                    pa[ks] = __builtin_bit_cast(bf16x8, t);
                }
#pragma unroll
                for (int d = 0; d < 4; d++) {
                    const int dh = d * 16 + lr;
#pragma unroll
                    for (int ks = 0; ks < 2; ks++) {
                        const int t = (ks * 4 + g) ^ (dh & 7);
                        bf16x8 v8 = ldfrag(&vbuf[s][dh][t * 8]);
                        oacc[rt * 4 + d] = __builtin_amdgcn_mfma_f32_16x16x32_bf16(pa[ks], v8, oacc[rt * 4 + d], 0, 0, 0);
                    }
                }
            }
        }
    }

    // finalize own (oi, s) partial outputs
    float ofin[2][4][4];
#pragma unroll
    for (int rt = 0; rt < 2; rt++)
#pragma unroll
        for (int r = 0; r < 4; r++) {
            float inv = __builtin_amdgcn_rcpf(lrun[rt * 4 + r]);
#pragma unroll
            for (int d = 0; d < 4; d++) ofin[rt][d][r] = oacc[rt * 4 + d][r] * inv;
        }

    // combine the two key-sources through LDS (reuse kbuf as f32 comb buffer)
    float (*comb)[32][64] = (float(*)[32][64])&kbuf[0][0][0][0];  // [oi*2+wq][row][dh]
    const int ci = oi * 2 + wq;
    __syncthreads();
    if (s == 0) {
#pragma unroll
        for (int rt = 0; rt < 2; rt++)
#pragma unroll
            for (int d = 0; d < 4; d++)
#pragma unroll
                for (int r = 0; r < 4; r++)
                    comb[ci][rt * 16 + g * 4 + r][d * 16 + lr] = ofin[rt][d][r];
    }
    __syncthreads();
    if (s == 1) {
        float* ob = out + (size_t)oi * ((size_t)NB * L * D);
#pragma unroll
        for (int rt = 0; rt < 2; rt++)
#pragma unroll
            for (int r = 0; r < 4; r++) {
                int row = l0 + rt * 16 + g * 4 + r;
                float mr = maskrow[n * L + row];
#pragma unroll
                for (int d = 0; d < 4; d++) {
                    float v = 0.5f * (ofin[rt][d][r] + comb[ci][rt * 16 + g * 4 + r][d * 16 + lr]);
                    v = (mr > 0.f) ? v : 0.f;
                    ob[((size_t)n * L + row) * D + hh * DH + d * 16 + lr] = v;
                }
            }
    }
}

extern "C" void kernel_launch(void* const* d_in, const int* in_sizes, int n_in,
                              void* d_out, int out_size, void* d_ws, size_t ws_size,
                              hipStream_t stream) {
    const float* input1 = (const float*)d_in[0];
    const float* mask1  = (const float*)d_in[1];
    const float* input2 = (const float*)d_in[2];
    const float* mask2  = (const float*)d_in[3];
    u16*   ws  = (u16*)d_ws;
    float* out = (float*)d_out;

    k_split_all<<<5632, 256, 0, stream>>>(input1, input2,
                                          (const float*)d_in[4], (const float*)d_in[5],
                                          (const float*)d_in[6], (const float*)d_in[7],
                                          (const float*)d_in[8], (const float*)d_in[9], ws);
    k_vlen<<<8, 256, 0, stream>>>(mask1, mask2, (int*)(ws + OFF_VLEN));
    k_proj<<<1536, 256, 0, stream>>>(ws);
    k_attn<<<512, 512, 0, stream>>>(ws, mask1, mask2, out);
}

// Round 5
// 262.564 us; speedup vs baseline: 1.5937x; 1.5937x over previous
//
#include <hip/hip_runtime.h>

#define DEV static __device__ __forceinline__

typedef unsigned short u16;
typedef short bf16x8 __attribute__((ext_vector_type(8)));
typedef u16 u16x8v __attribute__((ext_vector_type(8)));
typedef u16 u16x4v __attribute__((ext_vector_type(4)));
typedef float f32x4 __attribute__((ext_vector_type(4)));

static constexpr int NB = 4, L = 1024, D = 512, H = 8, DH = 64;
static constexpr size_t E  = (size_t)NB * L * D;   // 2,097,152
static constexpr size_t WE = (size_t)D * D;        // 262,144

// d_ws layout in u16 units
static constexpr size_t OFF_X1H = 0;
static constexpr size_t OFF_X1L = OFF_X1H + E;
static constexpr size_t OFF_X2H = OFF_X1L + E;
static constexpr size_t OFF_X2L = OFF_X2H + E;
static constexpr size_t OFF_WH  = OFF_X2L + E;       // 6 x WE
static constexpr size_t OFF_WL  = OFF_WH + 6 * WE;   // 6 x WE
static constexpr size_t OFF_QKV = OFF_WL + 6 * WE;
// OFF_QKV + {0:q1h,1E:q1l,2E:k1h,3E:k1l,4E:q2h,5E:q2l,6E:k2h,7E:k2l,8E:v1t,9E:v2t}
// K stored dh-SWIZZLED (dh ^= (key&7)<<3); V^T stored key-SWIZZLED
// (key ^= (dh&7)<<3 within each 64-key tile) so linear global_load_lds staging
// yields bank-conflict-free ds_read_b128 fragments (rule #21).
static constexpr size_t OFF_VLEN = OFF_QKV + 10 * E; // int[8] (s*4+n)

DEV u16 f2bf(float x) {
    unsigned u = __builtin_bit_cast(unsigned, x);
    unsigned r = u + 0x7FFFu + ((u >> 16) & 1u);
    return (u16)(r >> 16);
}
DEV float bf2f(u16 h) {
    unsigned u = ((unsigned)h) << 16;
    return __builtin_bit_cast(float, u);
}
DEV bf16x8 ldfrag(const u16* p) {
    u16x8v t = *reinterpret_cast<const u16x8v*>(p);
    return __builtin_bit_cast(bf16x8, t);
}
typedef __attribute__((address_space(1))) const unsigned gas_u32;
typedef __attribute__((address_space(3))) unsigned las_u32;
DEV void gld16(const u16* g, u16* l) {
    __builtin_amdgcn_global_load_lds((gas_u32*)g, (las_u32*)l, 16, 0, 0);
}

// ---------------- fused split fp32 -> (hi, lo) bf16 for X1, X2, W0..W5 ----------------
__global__ __launch_bounds__(256) void k_split_all(const float* __restrict__ x1,
                                                   const float* __restrict__ x2,
                                                   const float* w0, const float* w1,
                                                   const float* w2, const float* w3,
                                                   const float* w4, const float* w5,
                                                   u16* __restrict__ ws) {
    int b = blockIdx.x;
    const float* src;
    u16 *hi, *lo;
    int i0;
    if (b < 2048)      { src = x1; hi = ws + OFF_X1H; lo = ws + OFF_X1L; i0 = b; }
    else if (b < 4096) { src = x2; hi = ws + OFF_X2H; lo = ws + OFF_X2L; i0 = b - 2048; }
    else {
        int wi = (b - 4096) >> 8;
        const float* wp[6] = {w0, w1, w2, w3, w4, w5};
        src = wp[wi];
        hi = ws + OFF_WH + (size_t)wi * WE;
        lo = ws + OFF_WL + (size_t)wi * WE;
        i0 = (b - 4096) & 255;
    }
    int i = i0 * 256 + threadIdx.x;
    float4 v = reinterpret_cast<const float4*>(src)[i];
    float xs[4] = {v.x, v.y, v.z, v.w};
    u16x4v h, l;
#pragma unroll
    for (int j = 0; j < 4; j++) {
        u16 hh = f2bf(xs[j]);
        h[j] = hh;
        l[j] = f2bf(xs[j] - bf2f(hh));
    }
    reinterpret_cast<u16x4v*>(hi)[i] = h;
    reinterpret_cast<u16x4v*>(lo)[i] = l;
}

// ---------------- valid-length per (src, n): prefix-mask sum ----------------
__global__ __launch_bounds__(256) void k_vlen(const float* __restrict__ m1,
                                              const float* __restrict__ m2,
                                              int* __restrict__ vl) {
    int b = blockIdx.x;            // 0..7 : s*4+n
    int s = b >> 2, n = b & 3;
    const float* m = (s ? m2 : m1) + n * L;
    float p = 0.f;
    for (int i = threadIdx.x; i < L; i += 256) p += m[i];
#pragma unroll
    for (int mk = 1; mk < 64; mk <<= 1) p += __shfl_xor(p, mk, 64);
    __shared__ float w4[4];
    if ((threadIdx.x & 63) == 0) w4[threadIdx.x >> 6] = p;
    __syncthreads();
    if (threadIdx.x == 0) vl[b] = (int)(w4[0] + w4[1] + w4[2] + w4[3] + 0.5f);
}

// ---------------- projections, 128x64 block tile, 32 rows/wave ----------------
__global__ __launch_bounds__(256) void k_proj(u16* __restrict__ ws) {
    const int b     = blockIdx.x;
    const int proj  = b >> 8;        // 0..5 : q1,k1,v1,q2,k2,v2
    const int rem   = b & 255;
    const int mtile = rem >> 3;
    const int ntile = rem & 7;
    const int tid   = threadIdx.x;
    const int w     = tid >> 6;
    const int lane  = tid & 63;
    const int lr    = lane & 15;
    const int g     = lane >> 4;

    const int src  = proj / 3;
    const int kind = proj % 3;
    const u16* Xh = ws + (src ? OFF_X2H : OFF_X1H);
    const u16* Xl = ws + (src ? OFF_X2L : OFF_X1L);
    const u16* Wh = ws + OFF_WH + (size_t)proj * WE;
    const u16* Wl = ws + OFF_WL + (size_t)proj * WE;

    const int m0 = mtile * 128 + w * 32;
    const int n0 = ntile * 64;

    f32x4 acc[2][4];
#pragma unroll
    for (int rb = 0; rb < 2; rb++)
#pragma unroll
        for (int cb = 0; cb < 4; cb++) acc[rb][cb] = {0.f, 0.f, 0.f, 0.f};

    const u16* xh0 = Xh + (size_t)(m0 + lr) * D + g * 8;
    const u16* xh1 = Xh + (size_t)(m0 + 16 + lr) * D + g * 8;
    const u16* xl0 = Xl + (size_t)(m0 + lr) * D + g * 8;
    const u16* xl1 = Xl + (size_t)(m0 + 16 + lr) * D + g * 8;
#pragma unroll 4
    for (int e = 0; e < D; e += 32) {
        bf16x8 ah0 = ldfrag(xh0 + e), ah1 = ldfrag(xh1 + e);
        bf16x8 al0 = ldfrag(xl0 + e), al1 = ldfrag(xl1 + e);
#pragma unroll
        for (int cb = 0; cb < 4; cb++) {
            const u16* pwh = Wh + (size_t)(n0 + cb * 16 + lr) * D + e + g * 8;
            const u16* pwl = Wl + (size_t)(n0 + cb * 16 + lr) * D + e + g * 8;
            bf16x8 bh = ldfrag(pwh);
            bf16x8 bl = ldfrag(pwl);
            acc[0][cb] = __builtin_amdgcn_mfma_f32_16x16x32_bf16(ah0, bh, acc[0][cb], 0, 0, 0);
            acc[0][cb] = __builtin_amdgcn_mfma_f32_16x16x32_bf16(ah0, bl, acc[0][cb], 0, 0, 0);
            acc[0][cb] = __builtin_amdgcn_mfma_f32_16x16x32_bf16(al0, bh, acc[0][cb], 0, 0, 0);
            acc[1][cb] = __builtin_amdgcn_mfma_f32_16x16x32_bf16(ah1, bh, acc[1][cb], 0, 0, 0);
            acc[1][cb] = __builtin_amdgcn_mfma_f32_16x16x32_bf16(ah1, bl, acc[1][cb], 0, 0, 0);
            acc[1][cb] = __builtin_amdgcn_mfma_f32_16x16x32_bf16(al1, bh, acc[1][cb], 0, 0, 0);
        }
    }

    if (kind < 2) {
        u16* dhi = ws + OFF_QKV + (size_t)(src * 4 + kind * 2) * E;
        u16* dlo = dhi + E;
#pragma unroll
        for (int rb = 0; rb < 2; rb++)
#pragma unroll
            for (int cb = 0; cb < 4; cb++) {
                int d  = n0 + cb * 16 + lr;
                int hh = d >> 6, dh = d & 63;
#pragma unroll
                for (int r = 0; r < 4; r++) {
                    int m = m0 + rb * 16 + g * 4 + r;
                    int n = m >> 10, li = m & 1023;
                    int dhs = kind ? (dh ^ ((li & 7) << 3)) : dh;   // K dh-swizzle
                    size_t idx = ((size_t)(n * H + hh) * L + li) * DH + dhs;
                    float v = acc[rb][cb][r];
                    u16 hv = f2bf(v);
                    dhi[idx] = hv;
                    dlo[idx] = f2bf(v - bf2f(hv));
                }
            }
    } else {
        u16* vt = ws + OFF_QKV + (size_t)(8 + src) * E;
#pragma unroll
        for (int rb = 0; rb < 2; rb++)
#pragma unroll
            for (int cb = 0; cb < 4; cb++) {
                int d  = n0 + cb * 16 + lr;
                int hh = d >> 6, dh = d & 63;
                int m  = m0 + rb * 16 + g * 4;
                int n  = m >> 10, li = m & 1023;
                int lis = li ^ ((dh & 7) << 3);   // V key-swizzle
                u16x4v pk;
#pragma unroll
                for (int r = 0; r < 4; r++) pk[r] = f2bf(acc[rb][cb][r]);
                *reinterpret_cast<u16x4v*>(vt + ((size_t)(n * H + hh) * DH + dh) * L + lis) = pk;
            }
    }
}

// ---------------- fused two-source flash attention ----------------
// grid 1024 blocks x 512 thr; block=(oi,n,h,qt), wave=(s, wq); 16 q-rows/wave.
// Double-buffered K/V LDS, stage-early pipeline, swapped-QK lane-local softmax.
__global__ __launch_bounds__(512) void k_attn(const u16* __restrict__ ws,
                                              float* __restrict__ out) {
    __shared__ __align__(16) u16 kbuf[2][2][2][64][64]; // [dbuf][src][hi/lo][key][dh-swz] 64KB
    __shared__ __align__(16) u16 vbuf[2][2][64][64];    // [dbuf][src][dh][key-swz]        32KB
    __shared__ __align__(16) u16 plds[8][16][64];       // per-wave P [query][key-swz]     16KB

    const int bid  = blockIdx.x;
    const int b    = ((bid & 7) << 7) | (bid >> 3);  // XCD-contiguous qt runs
    const int oi   = b >> 9;
    const int rem  = b & 511;
    const int qt   = rem & 15;
    const int hh   = (rem >> 4) & 7;
    const int n    = rem >> 7;
    const int tid  = threadIdx.x;
    const int w    = tid >> 6;
    const int s    = w >> 2;        // key source
    const int wq   = w & 3;         // q sub-tile
    const int lane = tid & 63;
    const int lr   = lane & 15;
    const int g    = lane >> 4;
    const int swz  = (lr & 7) << 3;

    const size_t nh = (size_t)(n * H + hh);
    const u16* Qh = ws + OFF_QKV + (size_t)(oi * 4) * E;
    const u16* Ql = Qh + E;
    const int* vl = (const int*)(ws + OFF_VLEN);
    const int vls = vl[s * 4 + n];    // valid keys for my source
    const int vlo = vl[oi * 4 + n];   // valid rows for my output

    const int l0 = qt * 64 + wq * 16;
    const size_t qbase = (nh * L + l0 + lr) * DH + g * 8;
    bf16x8 qh0 = ldfrag(Qh + qbase), qh1 = ldfrag(Qh + qbase + 32);
    bf16x8 ql0 = ldfrag(Ql + qbase), ql1 = ldfrag(Ql + qbase + 32);

    float mrun = -1e30f, lrun = 0.f;  // per-lane: query = lr (replicated over g)
    f32x4 oacc[4];
#pragma unroll
    for (int d = 0; d < 4; d++) oacc[d] = {0.f, 0.f, 0.f, 0.f};

    const int nkt0 = (vl[n] + 63) >> 6;
    const int nkt1 = (vl[4 + n] + 63) >> 6;
    const int mykt = s ? nkt1 : nkt0;
    const int nktmax = nkt0 > nkt1 ? nkt0 : nkt1;

    // staging: 48 x 1KB chunks per kt, 6 per wave
    const int lane8 = lane >> 3, lanec = lane & 7;
    const u16* gsrc[6];
    u16* ldst[6];
    int ginc[6], lstr[6];
#pragma unroll
    for (int i = 0; i < 6; i++) {
        const int c  = w * 6 + i;
        const int cs = c / 24, cr = c % 24;
        if (cr < 16) {
            const int hl = cr >> 3, rr = cr & 7;
            const u16* K = ws + OFF_QKV + (size_t)(2 + cs * 4 + hl) * E;
            gsrc[i] = K + (nh * L + rr * 8 + lane8) * DH + lanec * 8;
            ldst[i] = &kbuf[0][cs][hl][rr * 8][0];
            ginc[i] = 64 * DH;
            lstr[i] = 2 * 2 * 64 * 64;   // dbuf stride within kbuf
        } else {
            const int rr = cr - 16;
            const u16* V = ws + OFF_QKV + (size_t)(8 + cs) * E;
            gsrc[i] = V + (nh * DH + rr * 8 + lane8) * L + lanec * 8;
            ldst[i] = &vbuf[0][cs][rr * 8][0];
            ginc[i] = 64;
            lstr[i] = 2 * 64 * 64;       // dbuf stride within vbuf
        }
    }

    // prologue: stage tile 0 into buffer 0
#pragma unroll
    for (int i = 0; i < 6; i++) { gld16(gsrc[i], ldst[i]); gsrc[i] += ginc[i]; }
    __syncthreads();   // vmcnt(0) drain + barrier

    int cur = 0;
    const int srcb = (lane & 48) + ((lane >> 4) << 2);  // lane holding row-state

#pragma unroll 1
    for (int kt = 0; kt < nktmax; kt++) {
        // stage next tile into the other buffer (issue-early, T3)
        if (kt + 1 < nktmax) {
            const int nb = cur ^ 1;
#pragma unroll
            for (int i = 0; i < 6; i++) { gld16(gsrc[i], ldst[i] + nb * lstr[i]); gsrc[i] += ginc[i]; }
        }

        if (kt < mykt) {
            // --- QK^T swapped: C[key=g*4+r][query=lr] ---
            f32x4 sfr[4];
#pragma unroll
            for (int j = 0; j < 4; j++) {
                const int row = j * 16 + lr;
                const int t0 = g ^ (row & 7);
                const int t1 = (g + 4) ^ (row & 7);
                bf16x8 kh0 = ldfrag(&kbuf[cur][s][0][row][t0 * 8]);
                bf16x8 kh1 = ldfrag(&kbuf[cur][s][0][row][t1 * 8]);
                bf16x8 kl0 = ldfrag(&kbuf[cur][s][1][row][t0 * 8]);
                bf16x8 kl1 = ldfrag(&kbuf[cur][s][1][row][t1 * 8]);
                f32x4 a = {0.f, 0.f, 0.f, 0.f};
                a = __builtin_amdgcn_mfma_f32_16x16x32_bf16(kh0, qh0, a, 0, 0, 0);
                a = __builtin_amdgcn_mfma_f32_16x16x32_bf16(kh1, qh1, a, 0, 0, 0);
                a = __builtin_amdgcn_mfma_f32_16x16x32_bf16(kl0, qh0, a, 0, 0, 0);
                a = __builtin_amdgcn_mfma_f32_16x16x32_bf16(kl1, qh1, a, 0, 0, 0);
                a = __builtin_amdgcn_mfma_f32_16x16x32_bf16(kh0, ql0, a, 0, 0, 0);
                a = __builtin_amdgcn_mfma_f32_16x16x32_bf16(kh1, ql1, a, 0, 0, 0);
                sfr[j] = a;
            }
            // --- lane-local online softmax (query = lr) ---
            const int kb0 = kt * 64 + g * 4;
            float tm = -1e30f;
#pragma unroll
            for (int j = 0; j < 4; j++)
#pragma unroll
                for (int r = 0; r < 4; r++) {
                    float sv = (kb0 + j * 16 + r < vls) ? sfr[j][r] : -1e30f;
                    sfr[j][r] = sv;
                    tm = fmaxf(tm, sv);
                }
            tm = fmaxf(tm, __shfl_xor(tm, 16, 64));
            tm = fmaxf(tm, __shfl_xor(tm, 32, 64));
            float mnew = fmaxf(mrun, tm);
            float sc = __expf(mrun - mnew);
            mrun = mnew;
            float ps = 0.f;
#pragma unroll
            for (int j = 0; j < 4; j++) {
                float e0 = __expf(sfr[j][0] - mnew), e1 = __expf(sfr[j][1] - mnew);
                float e2 = __expf(sfr[j][2] - mnew), e3 = __expf(sfr[j][3] - mnew);
                ps += (e0 + e1) + (e2 + e3);
                unsigned p01 = (unsigned)f2bf(e0) | ((unsigned)f2bf(e1) << 16);
                unsigned p23 = (unsigned)f2bf(e2) | ((unsigned)f2bf(e3) << 16);
                const int kk = j * 16 + g * 4;
                *reinterpret_cast<unsigned*>(&plds[w][lr][kk ^ swz])       = p01;
                *reinterpret_cast<unsigned*>(&plds[w][lr][(kk + 2) ^ swz]) = p23;
            }
            ps += __shfl_xor(ps, 16, 64);
            ps += __shfl_xor(ps, 32, 64);
            lrun = lrun * sc + ps;
            // broadcast rescale factor to the lanes owning rows g*4+r
            float scq0 = __shfl(sc, srcb + 0, 64), scq1 = __shfl(sc, srcb + 1, 64);
            float scq2 = __shfl(sc, srcb + 2, 64), scq3 = __shfl(sc, srcb + 3, 64);
#pragma unroll
            for (int d = 0; d < 4; d++) {
                oacc[d][0] *= scq0; oacc[d][1] *= scq1;
                oacc[d][2] *= scq2; oacc[d][3] *= scq3;
            }
            // --- P fragments + PV ---
            bf16x8 pa[2];
#pragma unroll
            for (int ks = 0; ks < 2; ks++) {
                int base = (ks * 32 + g * 8) ^ swz;
                u16x8v t = *reinterpret_cast<const u16x8v*>(&plds[w][lr][base]);
                pa[ks] = __builtin_bit_cast(bf16x8, t);
            }
#pragma unroll
            for (int d = 0; d < 4; d++) {
                const int dh = d * 16 + lr;
#pragma unroll
                for (int ks = 0; ks < 2; ks++) {
                    const int t = (ks * 4 + g) ^ (dh & 7);
                    bf16x8 v8 = ldfrag(&vbuf[cur][s][dh][t * 8]);
                    oacc[d] = __builtin_amdgcn_mfma_f32_16x16x32_bf16(pa[ks], v8, oacc[d], 0, 0, 0);
                }
            }
        }
        __syncthreads();   // drains vmcnt: next buffer staged & this buffer free
        cur ^= 1;
    }

    // finalize: divide rows g*4+r by their lrun (held at lane lr=row)
    float lq[4];
#pragma unroll
    for (int r = 0; r < 4; r++) lq[r] = __shfl(lrun, srcb + r, 64);
    float ofin[4][4];
#pragma unroll
    for (int r = 0; r < 4; r++) {
        float inv = __builtin_amdgcn_rcpf(lq[r]);
#pragma unroll
        for (int d = 0; d < 4; d++) ofin[d][r] = oacc[d][r] * inv;
    }

    // combine the two key-sources through LDS (reuse kbuf as f32 comb buffer)
    float (*comb)[16][64] = (float(*)[16][64])&kbuf[0][0][0][0][0];
    if (s == 0) {
#pragma unroll
        for (int d = 0; d < 4; d++)
#pragma unroll
            for (int r = 0; r < 4; r++) comb[wq][g * 4 + r][d * 16 + lr] = ofin[d][r];
    }
    __syncthreads();
    if (s == 1) {
        float* ob = out + (size_t)oi * ((size_t)NB * L * D);
#pragma unroll
        for (int r = 0; r < 4; r++) {
            int row = l0 + g * 4 + r;
#pragma unroll
            for (int d = 0; d < 4; d++) {
                float v = 0.5f * (ofin[d][r] + comb[wq][g * 4 + r][d * 16 + lr]);
                v = (row < vlo) ? v : 0.f;
                ob[((size_t)n * L + row) * D + hh * DH + d * 16 + lr] = v;
            }
        }
    }
}

extern "C" void kernel_launch(void* const* d_in, const int* in_sizes, int n_in,
                              void* d_out, int out_size, void* d_ws, size_t ws_size,
                              hipStream_t stream) {
    const float* input1 = (const float*)d_in[0];
    const float* mask1  = (const float*)d_in[1];
    const float* input2 = (const float*)d_in[2];
    const float* mask2  = (const float*)d_in[3];
    u16*   ws  = (u16*)d_ws;
    float* out = (float*)d_out;

    k_split_all<<<5632, 256, 0, stream>>>(input1, input2,
                                          (const float*)d_in[4], (const float*)d_in[5],
                                          (const float*)d_in[6], (const float*)d_in[7],
                                          (const float*)d_in[8], (const float*)d_in[9], ws);
    k_vlen<<<8, 256, 0, stream>>>(mask1, mask2, (int*)(ws + OFF_VLEN));
    k_proj<<<1536, 256, 0, stream>>>(ws);
    k_attn<<<1024, 512, 0, stream>>>(ws, out);
}

// Round 6
// 187.320 us; speedup vs baseline: 2.2338x; 1.4017x over previous
//
#include <hip/hip_runtime.h>

#define DEV static __device__ __forceinline__

typedef unsigned short u16;
typedef short bf16x8 __attribute__((ext_vector_type(8)));
typedef u16 u16x8v __attribute__((ext_vector_type(8)));
typedef u16 u16x4v __attribute__((ext_vector_type(4)));
typedef float f32x4 __attribute__((ext_vector_type(4)));

static constexpr int NB = 4, L = 1024, D = 512, H = 8, DH = 64;
static constexpr size_t E  = (size_t)NB * L * D;   // 2,097,152
static constexpr size_t WE = (size_t)D * D;        // 262,144

// d_ws layout in u16 units
// X1/X2/W are stored CHUNK-SWIZZLED: element e of row m lives at e ^ ((m&7)<<3)
// (bits 3-5, self-contained within each 64-u16/128B segment) so linear
// global_load_lds staging in k_proj yields conflict-free ds_read_b128.
static constexpr size_t OFF_X1H = 0;
static constexpr size_t OFF_X1L = OFF_X1H + E;
static constexpr size_t OFF_X2H = OFF_X1L + E;
static constexpr size_t OFF_X2L = OFF_X2H + E;
static constexpr size_t OFF_WH  = OFF_X2L + E;       // 6 x WE
static constexpr size_t OFF_WL  = OFF_WH + 6 * WE;   // 6 x WE
static constexpr size_t OFF_QKV = OFF_WL + 6 * WE;
// OFF_QKV + {0:q1h,1E:q1l,2E:k1h,3E:k1l,4E:q2h,5E:q2l,6E:k2h,7E:k2l,8E:v1t,9E:v2t}
// K stored dh-SWIZZLED (dh ^= (key&7)<<3); V^T stored key-SWIZZLED
// (key ^= (dh&7)<<3 within each 64-key tile).
static constexpr size_t OFF_VLEN = OFF_QKV + 10 * E; // int[8] (s*4+n)

DEV u16 f2bf(float x) {
    unsigned u = __builtin_bit_cast(unsigned, x);
    unsigned r = u + 0x7FFFu + ((u >> 16) & 1u);
    return (u16)(r >> 16);
}
DEV float bf2f(u16 h) {
    unsigned u = ((unsigned)h) << 16;
    return __builtin_bit_cast(float, u);
}
DEV bf16x8 ldfrag(const u16* p) {
    u16x8v t = *reinterpret_cast<const u16x8v*>(p);
    return __builtin_bit_cast(bf16x8, t);
}
typedef __attribute__((address_space(1))) const unsigned gas_u32;
typedef __attribute__((address_space(3))) unsigned las_u32;
DEV void gld16(const u16* g, u16* l) {
    __builtin_amdgcn_global_load_lds((gas_u32*)g, (las_u32*)l, 16, 0, 0);
}

// ---------------- fused split fp32 -> (hi, lo) bf16, chunk-swizzled ----------------
__global__ __launch_bounds__(256) void k_split_all(const float* __restrict__ x1,
                                                   const float* __restrict__ x2,
                                                   const float* w0, const float* w1,
                                                   const float* w2, const float* w3,
                                                   const float* w4, const float* w5,
                                                   u16* __restrict__ ws) {
    int b = blockIdx.x;
    const float* src;
    u16 *hi, *lo;
    int i0;
    if (b < 2048)      { src = x1; hi = ws + OFF_X1H; lo = ws + OFF_X1L; i0 = b; }
    else if (b < 4096) { src = x2; hi = ws + OFF_X2H; lo = ws + OFF_X2L; i0 = b - 2048; }
    else {
        int wi = (b - 4096) >> 8;
        const float* wp[6] = {w0, w1, w2, w3, w4, w5};
        src = wp[wi];
        hi = ws + OFF_WH + (size_t)wi * WE;
        lo = ws + OFF_WL + (size_t)wi * WE;
        i0 = (b - 4096) & 255;
    }
    int i = i0 * 256 + threadIdx.x;
    float4 v = reinterpret_cast<const float4*>(src)[i];
    float xs[4] = {v.x, v.y, v.z, v.w};
    u16x4v h, l;
#pragma unroll
    for (int j = 0; j < 4; j++) {
        u16 hh = f2bf(xs[j]);
        h[j] = hh;
        l[j] = f2bf(xs[j] - bf2f(hh));
    }
    // chunk-swizzle: idx = m*512 + e ; store at m*512 + (e ^ ((m&7)<<3))
    int idx = i * 4;
    int m = idx >> 9, e = idx & 511;
    int o = (m << 9) | (e ^ ((m & 7) << 3));
    *reinterpret_cast<u16x4v*>(hi + o) = h;
    *reinterpret_cast<u16x4v*>(lo + o) = l;
}

// ---------------- valid-length per (src, n): prefix-mask sum ----------------
__global__ __launch_bounds__(256) void k_vlen(const float* __restrict__ m1,
                                              const float* __restrict__ m2,
                                              int* __restrict__ vl) {
    int b = blockIdx.x;            // 0..7 : s*4+n
    int s = b >> 2, n = b & 3;
    const float* m = (s ? m2 : m1) + n * L;
    float p = 0.f;
    for (int i = threadIdx.x; i < L; i += 256) p += m[i];
#pragma unroll
    for (int mk = 1; mk < 64; mk <<= 1) p += __shfl_xor(p, mk, 64);
    __shared__ float w4[4];
    if ((threadIdx.x & 63) == 0) w4[threadIdx.x >> 6] = p;
    __syncthreads();
    if (threadIdx.x == 0) vl[b] = (int)(w4[0] + w4[1] + w4[2] + w4[3] + 0.5f);
}

// ---------------- projections: LDS-staged 128x128 tile, BK=64 ----------------
// grid: 6 proj x 32 mtiles x 4 ntiles = 768 blocks of 256 threads (4 waves 2x2).
__global__ __launch_bounds__(256) void k_proj(u16* __restrict__ ws) {
    __shared__ __align__(16) u16 ta[2][128][64];  // [hi/lo][m][k chunk-swz] 32KB
    __shared__ __align__(16) u16 tb[2][128][64];  // [hi/lo][n][k chunk-swz] 32KB

    const int b     = blockIdx.x;
    const int proj  = b >> 7;        // 0..5 : q1,k1,v1,q2,k2,v2
    const int rem   = b & 127;
    const int mtile = rem >> 2;      // 32 tiles of 128 rows
    const int ntile = rem & 3;       // 4 tiles of 128 cols
    const int tid   = threadIdx.x;
    const int w     = tid >> 6;
    const int lane  = tid & 63;
    const int lr    = lane & 15;
    const int g     = lane >> 4;
    const int wr    = w >> 1, wc = w & 1;

    const int src  = proj / 3;
    const int kind = proj % 3;
    const u16* Xh = ws + (src ? OFF_X2H : OFF_X1H);
    const u16* Xl = ws + (src ? OFF_X2L : OFF_X1L);
    const u16* Wh = ws + OFF_WH + (size_t)proj * WE;
    const u16* Wl = ws + OFF_WL + (size_t)proj * WE;

    const int m0 = mtile * 128, n0 = ntile * 128;

    // staging: wave w stages rows [w*32, w*32+32) of each of the 4 pieces,
    // 4 instrs x 8 rows; lane -> row = lane>>3, chunk = lane&7 (16B).
    const int lrow = lane >> 3, lcol = lane & 7;
    const u16* gA0 = Xh + (size_t)(m0 + w * 32 + lrow) * 512 + lcol * 8;
    const u16* gA1 = Xl + (size_t)(m0 + w * 32 + lrow) * 512 + lcol * 8;
    const u16* gB0 = Wh + (size_t)(n0 + w * 32 + lrow) * 512 + lcol * 8;
    const u16* gB1 = Wl + (size_t)(n0 + w * 32 + lrow) * 512 + lcol * 8;

    f32x4 acc[4][4];
#pragma unroll
    for (int fr = 0; fr < 4; fr++)
#pragma unroll
        for (int cb = 0; cb < 4; cb++) acc[fr][cb] = {0.f, 0.f, 0.f, 0.f};

#pragma unroll 1
    for (int step = 0; step < 8; step++) {
        __syncthreads();   // previous compute done; LDS free
#pragma unroll
        for (int i = 0; i < 4; i++) {
            const int roff = w * 32 + i * 8;
            const int e0 = step * 64;
            gld16(gA0 + e0 + i * (8 * 512), &ta[0][roff][0]);
            gld16(gA1 + e0 + i * (8 * 512), &ta[1][roff][0]);
            gld16(gB0 + e0 + i * (8 * 512), &tb[0][roff][0]);
            gld16(gB1 + e0 + i * (8 * 512), &tb[1][roff][0]);
        }
        __syncthreads();   // vmcnt drained: staged tile visible

#pragma unroll
        for (int ks = 0; ks < 2; ks++) {
            bf16x8 ah[4], al[4];
#pragma unroll
            for (int fr = 0; fr < 4; fr++) {
                const int row = wr * 64 + fr * 16 + lr;
                const int ch = (ks * 4 + g) ^ (row & 7);
                ah[fr] = ldfrag(&ta[0][row][ch * 8]);
                al[fr] = ldfrag(&ta[1][row][ch * 8]);
            }
#pragma unroll
            for (int cb = 0; cb < 4; cb++) {
                const int rowb = wc * 64 + cb * 16 + lr;
                const int chb = (ks * 4 + g) ^ (rowb & 7);
                bf16x8 bh = ldfrag(&tb[0][rowb][chb * 8]);
                bf16x8 bl = ldfrag(&tb[1][rowb][chb * 8]);
#pragma unroll
                for (int fr = 0; fr < 4; fr++) {
                    acc[fr][cb] = __builtin_amdgcn_mfma_f32_16x16x32_bf16(ah[fr], bh, acc[fr][cb], 0, 0, 0);
                    acc[fr][cb] = __builtin_amdgcn_mfma_f32_16x16x32_bf16(ah[fr], bl, acc[fr][cb], 0, 0, 0);
                    acc[fr][cb] = __builtin_amdgcn_mfma_f32_16x16x32_bf16(al[fr], bh, acc[fr][cb], 0, 0, 0);
                }
            }
        }
    }

    // epilogue: C col = n0 + wc*64 + cb*16 + lr, row m = m0 + wr*64 + fr*16 + g*4 + r
    if (kind < 2) {
        u16* dhi = ws + OFF_QKV + (size_t)(src * 4 + kind * 2) * E;
        u16* dlo = dhi + E;
#pragma unroll
        for (int fr = 0; fr < 4; fr++)
#pragma unroll
            for (int cb = 0; cb < 4; cb++) {
                int d  = n0 + wc * 64 + cb * 16 + lr;
                int hh = d >> 6, dh = d & 63;
#pragma unroll
                for (int r = 0; r < 4; r++) {
                    int m = m0 + wr * 64 + fr * 16 + g * 4 + r;
                    int n = m >> 10, li = m & 1023;
                    int dhs = kind ? (dh ^ ((li & 7) << 3)) : dh;   // K dh-swizzle
                    size_t idx = ((size_t)(n * H + hh) * L + li) * DH + dhs;
                    float v = acc[fr][cb][r];
                    u16 hv = f2bf(v);
                    dhi[idx] = hv;
                    dlo[idx] = f2bf(v - bf2f(hv));
                }
            }
    } else {
        u16* vt = ws + OFF_QKV + (size_t)(8 + src) * E;
#pragma unroll
        for (int fr = 0; fr < 4; fr++)
#pragma unroll
            for (int cb = 0; cb < 4; cb++) {
                int d  = n0 + wc * 64 + cb * 16 + lr;
                int hh = d >> 6, dh = d & 63;
                int m  = m0 + wr * 64 + fr * 16 + g * 4;
                int n  = m >> 10, li = m & 1023;
                int lis = li ^ ((dh & 7) << 3);   // V key-swizzle
                u16x4v pk;
#pragma unroll
                for (int r = 0; r < 4; r++) pk[r] = f2bf(acc[fr][cb][r]);
                *reinterpret_cast<u16x4v*>(vt + ((size_t)(n * H + hh) * DH + dh) * L + lis) = pk;
            }
    }
}

// ---------------- fused two-source flash attention ----------------
// grid 1024 blocks x 512 thr; block=(oi,n,h,qt), wave=(s, wq); 16 q-rows/wave.
// Double-buffered K/V LDS, stage-early pipeline, swapped-QK lane-local softmax.
__global__ __launch_bounds__(512) void k_attn(const u16* __restrict__ ws,
                                              float* __restrict__ out) {
    __shared__ __align__(16) u16 kbuf[2][2][2][64][64]; // [dbuf][src][hi/lo][key][dh-swz] 64KB
    __shared__ __align__(16) u16 vbuf[2][2][64][64];    // [dbuf][src][dh][key-swz]        32KB
    __shared__ __align__(16) u16 plds[8][16][72];       // per-wave P, padded rows (144B)  18KB

    const int bid  = blockIdx.x;
    const int b    = ((bid & 7) << 7) | (bid >> 3);  // XCD-contiguous qt runs
    const int oi   = b >> 9;
    const int rem  = b & 511;
    const int qt   = rem & 15;
    const int hh   = (rem >> 4) & 7;
    const int n    = rem >> 7;
    const int tid  = threadIdx.x;
    const int w    = tid >> 6;
    const int s    = w >> 2;        // key source
    const int wq   = w & 3;         // q sub-tile
    const int lane = tid & 63;
    const int lr   = lane & 15;
    const int g    = lane >> 4;
    const int swz  = (lr & 7) << 3;

    const size_t nh = (size_t)(n * H + hh);
    const u16* Qh = ws + OFF_QKV + (size_t)(oi * 4) * E;
    const u16* Ql = Qh + E;
    const int* vl = (const int*)(ws + OFF_VLEN);
    const int vls = vl[s * 4 + n];    // valid keys for my source
    const int vlo = vl[oi * 4 + n];   // valid rows for my output

    const int l0 = qt * 64 + wq * 16;
    const size_t qbase = (nh * L + l0 + lr) * DH + g * 8;
    bf16x8 qh0 = ldfrag(Qh + qbase), qh1 = ldfrag(Qh + qbase + 32);
    bf16x8 ql0 = ldfrag(Ql + qbase), ql1 = ldfrag(Ql + qbase + 32);

    float mrun = -1e30f, lrun = 0.f;  // per-lane: query = lr (replicated over g)
    f32x4 oacc[4];
#pragma unroll
    for (int d = 0; d < 4; d++) oacc[d] = {0.f, 0.f, 0.f, 0.f};

    const int nkt0 = (vl[n] + 63) >> 6;
    const int nkt1 = (vl[4 + n] + 63) >> 6;
    const int mykt = s ? nkt1 : nkt0;
    const int nktmax = nkt0 > nkt1 ? nkt0 : nkt1;

    // staging: 48 x 1KB chunks per kt, 6 per wave
    const int lane8 = lane >> 3, lanec = lane & 7;
    const u16* gsrc[6];
    u16* ldst[6];
    int ginc[6], lstr[6];
#pragma unroll
    for (int i = 0; i < 6; i++) {
        const int c  = w * 6 + i;
        const int cs = c / 24, cr = c % 24;
        if (cr < 16) {
            const int hl = cr >> 3, rr = cr & 7;
            const u16* K = ws + OFF_QKV + (size_t)(2 + cs * 4 + hl) * E;
            gsrc[i] = K + (nh * L + rr * 8 + lane8) * DH + lanec * 8;
            ldst[i] = &kbuf[0][cs][hl][rr * 8][0];
            ginc[i] = 64 * DH;
            lstr[i] = 2 * 2 * 64 * 64;   // dbuf stride within kbuf
        } else {
            const int rr = cr - 16;
            const u16* V = ws + OFF_QKV + (size_t)(8 + cs) * E;
            gsrc[i] = V + (nh * DH + rr * 8 + lane8) * L + lanec * 8;
            ldst[i] = &vbuf[0][cs][rr * 8][0];
            ginc[i] = 64;
            lstr[i] = 2 * 64 * 64;       // dbuf stride within vbuf
        }
    }

    // prologue: stage tile 0 into buffer 0
#pragma unroll
    for (int i = 0; i < 6; i++) { gld16(gsrc[i], ldst[i]); gsrc[i] += ginc[i]; }
    __syncthreads();   // vmcnt(0) drain + barrier

    int cur = 0;
    const int srcb = (lane & 48) + ((lane >> 4) << 2);  // lane holding row-state

#pragma unroll 1
    for (int kt = 0; kt < nktmax; kt++) {
        // stage next tile into the other buffer (issue-early, T3)
        if (kt + 1 < nktmax) {
            const int nb = cur ^ 1;
#pragma unroll
            for (int i = 0; i < 6; i++) { gld16(gsrc[i], ldst[i] + nb * lstr[i]); gsrc[i] += ginc[i]; }
        }

        if (kt < mykt) {
            // --- QK^T swapped: C[key=g*4+r][query=lr] ---
            f32x4 sfr[4];
#pragma unroll
            for (int j = 0; j < 4; j++) {
                const int row = j * 16 + lr;
                const int t0 = g ^ (row & 7);
                const int t1 = (g + 4) ^ (row & 7);
                bf16x8 kh0 = ldfrag(&kbuf[cur][s][0][row][t0 * 8]);
                bf16x8 kh1 = ldfrag(&kbuf[cur][s][0][row][t1 * 8]);
                bf16x8 kl0 = ldfrag(&kbuf[cur][s][1][row][t0 * 8]);
                bf16x8 kl1 = ldfrag(&kbuf[cur][s][1][row][t1 * 8]);
                f32x4 a = {0.f, 0.f, 0.f, 0.f};
                a = __builtin_amdgcn_mfma_f32_16x16x32_bf16(kh0, qh0, a, 0, 0, 0);
                a = __builtin_amdgcn_mfma_f32_16x16x32_bf16(kh1, qh1, a, 0, 0, 0);
                a = __builtin_amdgcn_mfma_f32_16x16x32_bf16(kl0, qh0, a, 0, 0, 0);
                a = __builtin_amdgcn_mfma_f32_16x16x32_bf16(kl1, qh1, a, 0, 0, 0);
                a = __builtin_amdgcn_mfma_f32_16x16x32_bf16(kh0, ql0, a, 0, 0, 0);
                a = __builtin_amdgcn_mfma_f32_16x16x32_bf16(kh1, ql1, a, 0, 0, 0);
                sfr[j] = a;
            }
            // --- lane-local online softmax (query = lr) ---
            const int kb0 = kt * 64 + g * 4;
            float tm = -1e30f;
#pragma unroll
            for (int j = 0; j < 4; j++)
#pragma unroll
                for (int r = 0; r < 4; r++) {
                    float sv = (kb0 + j * 16 + r < vls) ? sfr[j][r] : -1e30f;
                    sfr[j][r] = sv;
                    tm = fmaxf(tm, sv);
                }
            tm = fmaxf(tm, __shfl_xor(tm, 16, 64));
            tm = fmaxf(tm, __shfl_xor(tm, 32, 64));
            float mnew = fmaxf(mrun, tm);
            float sc = __expf(mrun - mnew);
            mrun = mnew;
            float ps = 0.f;
#pragma unroll
            for (int j = 0; j < 4; j++) {
                float e0 = __expf(sfr[j][0] - mnew), e1 = __expf(sfr[j][1] - mnew);
                float e2 = __expf(sfr[j][2] - mnew), e3 = __expf(sfr[j][3] - mnew);
                ps += (e0 + e1) + (e2 + e3);
                unsigned p01 = (unsigned)f2bf(e0) | ((unsigned)f2bf(e1) << 16);
                unsigned p23 = (unsigned)f2bf(e2) | ((unsigned)f2bf(e3) << 16);
                const int kk = j * 16 + g * 4;
                uint2 pk; pk.x = p01; pk.y = p23;
                *reinterpret_cast<uint2*>(&plds[w][lr][kk ^ swz]) = pk;
            }
            ps += __shfl_xor(ps, 16, 64);
            ps += __shfl_xor(ps, 32, 64);
            lrun = lrun * sc + ps;
            // broadcast rescale factor to the lanes owning rows g*4+r
            float scq0 = __shfl(sc, srcb + 0, 64), scq1 = __shfl(sc, srcb + 1, 64);
            float scq2 = __shfl(sc, srcb + 2, 64), scq3 = __shfl(sc, srcb + 3, 64);
#pragma unroll
            for (int d = 0; d < 4; d++) {
                oacc[d][0] *= scq0; oacc[d][1] *= scq1;
                oacc[d][2] *= scq2; oacc[d][3] *= scq3;
            }
            // --- P fragments + PV ---
            bf16x8 pa[2];
#pragma unroll
            for (int ks = 0; ks < 2; ks++) {
                int base = (ks * 32 + g * 8) ^ swz;
                u16x8v t = *reinterpret_cast<const u16x8v*>(&plds[w][lr][base]);
                pa[ks] = __builtin_bit_cast(bf16x8, t);
            }
#pragma unroll
            for (int d = 0; d < 4; d++) {
                const int dh = d * 16 + lr;
#pragma unroll
                for (int ks = 0; ks < 2; ks++) {
                    const int t = (ks * 4 + g) ^ (dh & 7);
                    bf16x8 v8 = ldfrag(&vbuf[cur][s][dh][t * 8]);
                    oacc[d] = __builtin_amdgcn_mfma_f32_16x16x32_bf16(pa[ks], v8, oacc[d], 0, 0, 0);
                }
            }
        }
        __syncthreads();   // drains vmcnt: next buffer staged & this buffer free
        cur ^= 1;
    }

    // finalize: divide rows g*4+r by their lrun (held at lane lr=row)
    float lq[4];
#pragma unroll
    for (int r = 0; r < 4; r++) lq[r] = __shfl(lrun, srcb + r, 64);
    float ofin[4][4];
#pragma unroll
    for (int r = 0; r < 4; r++) {
        float inv = __builtin_amdgcn_rcpf(lq[r]);
#pragma unroll
        for (int d = 0; d < 4; d++) ofin[d][r] = oacc[d][r] * inv;
    }

    // combine the two key-sources through LDS (reuse kbuf as f32 comb buffer)
    float (*comb)[16][64] = (float(*)[16][64])&kbuf[0][0][0][0][0];
    if (s == 0) {
#pragma unroll
        for (int d = 0; d < 4; d++)
#pragma unroll
            for (int r = 0; r < 4; r++) comb[wq][g * 4 + r][d * 16 + lr] = ofin[d][r];
    }
    __syncthreads();
    if (s == 1) {
        float* ob = out + (size_t)oi * ((size_t)NB * L * D);
#pragma unroll
        for (int r = 0; r < 4; r++) {
            int row = l0 + g * 4 + r;
#pragma unroll
            for (int d = 0; d < 4; d++) {
                float v = 0.5f * (ofin[d][r] + comb[wq][g * 4 + r][d * 16 + lr]);
                v = (row < vlo) ? v : 0.f;
                ob[((size_t)n * L + row) * D + hh * DH + d * 16 + lr] = v;
            }
        }
    }
}

extern "C" void kernel_launch(void* const* d_in, const int* in_sizes, int n_in,
                              void* d_out, int out_size, void* d_ws, size_t ws_size,
                              hipStream_t stream) {
    const float* input1 = (const float*)d_in[0];
    const float* mask1  = (const float*)d_in[1];
    const float* input2 = (const float*)d_in[2];
    const float* mask2  = (const float*)d_in[3];
    u16*   ws  = (u16*)d_ws;
    float* out = (float*)d_out;

    k_split_all<<<5632, 256, 0, stream>>>(input1, input2,
                                          (const float*)d_in[4], (const float*)d_in[5],
                                          (const float*)d_in[6], (const float*)d_in[7],
                                          (const float*)d_in[8], (const float*)d_in[9], ws);
    k_vlen<<<8, 256, 0, stream>>>(mask1, mask2, (int*)(ws + OFF_VLEN));
    k_proj<<<768, 256, 0, stream>>>(ws);
    k_attn<<<1024, 512, 0, stream>>>(ws, out);
}

// Round 7
// 155.051 us; speedup vs baseline: 2.6987x; 1.2081x over previous
//
#include <hip/hip_runtime.h>

#define DEV static __device__ __forceinline__

typedef unsigned short u16;
typedef short bf16x8 __attribute__((ext_vector_type(8)));
typedef u16 u16x8v __attribute__((ext_vector_type(8)));
typedef u16 u16x4v __attribute__((ext_vector_type(4)));
typedef float f32x4 __attribute__((ext_vector_type(4)));

static constexpr int NB = 4, L = 1024, D = 512, H = 8, DH = 64;
static constexpr size_t E  = (size_t)NB * L * D;   // 2,097,152
static constexpr size_t WE = (size_t)D * D;        // 262,144

// d_ws layout in u16 units
// X1/X2/W stored CHUNK-SWIZZLED: element e of row m at e ^ ((m&7)<<3).
static constexpr size_t OFF_X1H = 0;
static constexpr size_t OFF_X1L = OFF_X1H + E;
static constexpr size_t OFF_X2H = OFF_X1L + E;
static constexpr size_t OFF_X2L = OFF_X2H + E;
static constexpr size_t OFF_WH  = OFF_X2L + E;       // 6 x WE
static constexpr size_t OFF_WL  = OFF_WH + 6 * WE;   // 6 x WE
static constexpr size_t OFF_QKV = OFF_WL + 6 * WE;
// OFF_QKV + {0:q1h,1E:q1l,2E:k1h,3E:k1l,4E:q2h,5E:q2l,6E:k2h,7E:k2l,8E:v1t,9E:v2t}
// Q stored PRE-SCALED by log2(e) (softmax runs in exp2 domain).
// K stored dh-SWIZZLED (dh ^= (key&7)<<3). V^T stored key-SWIZZLED within each
// 32-key tile (key ^= (dh&3)<<3) so linear global_load_lds staging yields
// bank-conflict-free ds_read_b128 fragments (rule #21).
static constexpr size_t OFF_VLEN = OFF_QKV + 10 * E; // int[8] (s*4+n)

DEV u16 f2bf(float x) {
    unsigned u = __builtin_bit_cast(unsigned, x);
    unsigned r = u + 0x7FFFu + ((u >> 16) & 1u);
    return (u16)(r >> 16);
}
DEV float bf2f(u16 h) {
    unsigned u = ((unsigned)h) << 16;
    return __builtin_bit_cast(float, u);
}
DEV bf16x8 ldfrag(const u16* p) {
    u16x8v t = *reinterpret_cast<const u16x8v*>(p);
    return __builtin_bit_cast(bf16x8, t);
}
typedef __attribute__((address_space(1))) const unsigned gas_u32;
typedef __attribute__((address_space(3))) unsigned las_u32;
DEV void gld16(const u16* g, u16* l) {
    __builtin_amdgcn_global_load_lds((gas_u32*)g, (las_u32*)l, 16, 0, 0);
}

// ---------------- fused split fp32 -> (hi, lo) bf16, chunk-swizzled ----------------
__global__ __launch_bounds__(256) void k_split_all(const float* __restrict__ x1,
                                                   const float* __restrict__ x2,
                                                   const float* w0, const float* w1,
                                                   const float* w2, const float* w3,
                                                   const float* w4, const float* w5,
                                                   u16* __restrict__ ws) {
    int b = blockIdx.x;
    const float* src;
    u16 *hi, *lo;
    int i0;
    if (b < 2048)      { src = x1; hi = ws + OFF_X1H; lo = ws + OFF_X1L; i0 = b; }
    else if (b < 4096) { src = x2; hi = ws + OFF_X2H; lo = ws + OFF_X2L; i0 = b - 2048; }
    else {
        int wi = (b - 4096) >> 8;
        const float* wp[6] = {w0, w1, w2, w3, w4, w5};
        src = wp[wi];
        hi = ws + OFF_WH + (size_t)wi * WE;
        lo = ws + OFF_WL + (size_t)wi * WE;
        i0 = (b - 4096) & 255;
    }
    int i = i0 * 256 + threadIdx.x;
    float4 v = reinterpret_cast<const float4*>(src)[i];
    float xs[4] = {v.x, v.y, v.z, v.w};
    u16x4v h, l;
#pragma unroll
    for (int j = 0; j < 4; j++) {
        u16 hh = f2bf(xs[j]);
        h[j] = hh;
        l[j] = f2bf(xs[j] - bf2f(hh));
    }
    // chunk-swizzle: idx = m*512 + e ; store at m*512 + (e ^ ((m&7)<<3))
    int idx = i * 4;
    int m = idx >> 9, e = idx & 511;
    int o = (m << 9) | (e ^ ((m & 7) << 3));
    *reinterpret_cast<u16x4v*>(hi + o) = h;
    *reinterpret_cast<u16x4v*>(lo + o) = l;
}

// ---------------- valid-length per (src, n): prefix-mask sum ----------------
__global__ __launch_bounds__(256) void k_vlen(const float* __restrict__ m1,
                                              const float* __restrict__ m2,
                                              int* __restrict__ vl) {
    int b = blockIdx.x;            // 0..7 : s*4+n
    int s = b >> 2, n = b & 3;
    const float* m = (s ? m2 : m1) + n * L;
    float p = 0.f;
    for (int i = threadIdx.x; i < L; i += 256) p += m[i];
#pragma unroll
    for (int mk = 1; mk < 64; mk <<= 1) p += __shfl_xor(p, mk, 64);
    __shared__ float w4[4];
    if ((threadIdx.x & 63) == 0) w4[threadIdx.x >> 6] = p;
    __syncthreads();
    if (threadIdx.x == 0) vl[b] = (int)(w4[0] + w4[1] + w4[2] + w4[3] + 0.5f);
}

// ---------------- projections: LDS-staged 128x128 tile, BK=64 ----------------
__global__ __launch_bounds__(256) void k_proj(u16* __restrict__ ws) {
    __shared__ __align__(16) u16 ta[2][128][64];
    __shared__ __align__(16) u16 tb[2][128][64];

    const int b     = blockIdx.x;
    const int proj  = b >> 7;        // 0..5 : q1,k1,v1,q2,k2,v2
    const int rem   = b & 127;
    const int mtile = rem >> 2;
    const int ntile = rem & 3;
    const int tid   = threadIdx.x;
    const int w     = tid >> 6;
    const int lane  = tid & 63;
    const int lr    = lane & 15;
    const int g     = lane >> 4;
    const int wr    = w >> 1, wc = w & 1;

    const int src  = proj / 3;
    const int kind = proj % 3;
    const u16* Xh = ws + (src ? OFF_X2H : OFF_X1H);
    const u16* Xl = ws + (src ? OFF_X2L : OFF_X1L);
    const u16* Wh = ws + OFF_WH + (size_t)proj * WE;
    const u16* Wl = ws + OFF_WL + (size_t)proj * WE;

    const int m0 = mtile * 128, n0 = ntile * 128;

    const int lrow = lane >> 3, lcol = lane & 7;
    const u16* gA0 = Xh + (size_t)(m0 + w * 32 + lrow) * 512 + lcol * 8;
    const u16* gA1 = Xl + (size_t)(m0 + w * 32 + lrow) * 512 + lcol * 8;
    const u16* gB0 = Wh + (size_t)(n0 + w * 32 + lrow) * 512 + lcol * 8;
    const u16* gB1 = Wl + (size_t)(n0 + w * 32 + lrow) * 512 + lcol * 8;

    f32x4 acc[4][4];
#pragma unroll
    for (int fr = 0; fr < 4; fr++)
#pragma unroll
        for (int cb = 0; cb < 4; cb++) acc[fr][cb] = {0.f, 0.f, 0.f, 0.f};

#pragma unroll 1
    for (int step = 0; step < 8; step++) {
        __syncthreads();
#pragma unroll
        for (int i = 0; i < 4; i++) {
            const int roff = w * 32 + i * 8;
            const int e0 = step * 64;
            gld16(gA0 + e0 + i * (8 * 512), &ta[0][roff][0]);
            gld16(gA1 + e0 + i * (8 * 512), &ta[1][roff][0]);
            gld16(gB0 + e0 + i * (8 * 512), &tb[0][roff][0]);
            gld16(gB1 + e0 + i * (8 * 512), &tb[1][roff][0]);
        }
        __syncthreads();

#pragma unroll
        for (int ks = 0; ks < 2; ks++) {
            bf16x8 ah[4], al[4];
#pragma unroll
            for (int fr = 0; fr < 4; fr++) {
                const int row = wr * 64 + fr * 16 + lr;
                const int ch = (ks * 4 + g) ^ (row & 7);
                ah[fr] = ldfrag(&ta[0][row][ch * 8]);
                al[fr] = ldfrag(&ta[1][row][ch * 8]);
            }
#pragma unroll
            for (int cb = 0; cb < 4; cb++) {
                const int rowb = wc * 64 + cb * 16 + lr;
                const int chb = (ks * 4 + g) ^ (rowb & 7);
                bf16x8 bh = ldfrag(&tb[0][rowb][chb * 8]);
                bf16x8 bl = ldfrag(&tb[1][rowb][chb * 8]);
#pragma unroll
                for (int fr = 0; fr < 4; fr++) {
                    acc[fr][cb] = __builtin_amdgcn_mfma_f32_16x16x32_bf16(ah[fr], bh, acc[fr][cb], 0, 0, 0);
                    acc[fr][cb] = __builtin_amdgcn_mfma_f32_16x16x32_bf16(ah[fr], bl, acc[fr][cb], 0, 0, 0);
                    acc[fr][cb] = __builtin_amdgcn_mfma_f32_16x16x32_bf16(al[fr], bh, acc[fr][cb], 0, 0, 0);
                }
            }
        }
    }

    if (kind < 2) {
        const float qscale = (kind == 0) ? 1.4426950408889634f : 1.0f;  // Q in log2 domain
        u16* dhi = ws + OFF_QKV + (size_t)(src * 4 + kind * 2) * E;
        u16* dlo = dhi + E;
#pragma unroll
        for (int fr = 0; fr < 4; fr++)
#pragma unroll
            for (int cb = 0; cb < 4; cb++) {
                int d  = n0 + wc * 64 + cb * 16 + lr;
                int hh = d >> 6, dh = d & 63;
#pragma unroll
                for (int r = 0; r < 4; r++) {
                    int m = m0 + wr * 64 + fr * 16 + g * 4 + r;
                    int n = m >> 10, li = m & 1023;
                    int dhs = kind ? (dh ^ ((li & 7) << 3)) : dh;   // K dh-swizzle
                    size_t idx = ((size_t)(n * H + hh) * L + li) * DH + dhs;
                    float v = acc[fr][cb][r] * qscale;
                    u16 hv = f2bf(v);
                    dhi[idx] = hv;
                    dlo[idx] = f2bf(v - bf2f(hv));
                }
            }
    } else {
        u16* vt = ws + OFF_QKV + (size_t)(8 + src) * E;
#pragma unroll
        for (int fr = 0; fr < 4; fr++)
#pragma unroll
            for (int cb = 0; cb < 4; cb++) {
                int d  = n0 + wc * 64 + cb * 16 + lr;
                int hh = d >> 6, dh = d & 63;
                int m  = m0 + wr * 64 + fr * 16 + g * 4;
                int n  = m >> 10, li = m & 1023;
                int lis = li ^ ((dh & 3) << 3);   // V key-swizzle within 32-key tile
                u16x4v pk;
#pragma unroll
                for (int r = 0; r < 4; r++) pk[r] = f2bf(acc[fr][cb][r]);
                *reinterpret_cast<u16x4v*>(vt + ((size_t)(n * H + hh) * DH + dh) * L + lis) = pk;
            }
    }
}

// ---------------- fused two-source flash attention, KVBLK=32 ----------------
// grid 1024 blocks x 512 thr; block=(oi,n,h,qt), wave=(s, wq); 16 q-rows/wave.
// 56KB LDS -> 2 blocks/CU. Double-buffered K/V, swapped-QK lane-local softmax
// in exp2 domain, defer-max rescale skip, setprio around MFMA clusters.
__global__ __launch_bounds__(512, 4) void k_attn(const u16* __restrict__ ws,
                                                 float* __restrict__ out) {
    __shared__ __align__(16) u16 kbuf[2][2][2][32][64]; // [dbuf][src][hi/lo][key][dh-swz] 32KB
    __shared__ __align__(16) u16 vbuf[2][2][64][32];    // [dbuf][src][dh][key-swz]        16KB
    __shared__ __align__(16) u16 plds[8][16][32];       // per-wave P [query][key-swz]      8KB

    const int bid  = blockIdx.x;
    const int b    = ((bid & 7) << 7) | (bid >> 3);  // XCD-contiguous qt runs
    const int oi   = b >> 9;
    const int rem  = b & 511;
    const int qt   = rem & 15;
    const int hh   = (rem >> 4) & 7;
    const int n    = rem >> 7;
    const int tid  = threadIdx.x;
    const int w    = tid >> 6;
    const int s    = w >> 2;        // key source
    const int wq   = w & 3;         // q sub-tile
    const int lane = tid & 63;
    const int lr   = lane & 15;
    const int g    = lane >> 4;
    const int swz  = (lr & 3) << 3;

    const size_t nh = (size_t)(n * H + hh);
    const u16* Qh = ws + OFF_QKV + (size_t)(oi * 4) * E;
    const u16* Ql = Qh + E;
    const int* vl = (const int*)(ws + OFF_VLEN);
    const int vls = vl[s * 4 + n];    // valid keys for my source
    const int vlo = vl[oi * 4 + n];   // valid rows for my output

    const int l0 = qt * 64 + wq * 16;
    const size_t qbase = (nh * L + l0 + lr) * DH + g * 8;
    bf16x8 qh0 = ldfrag(Qh + qbase), qh1 = ldfrag(Qh + qbase + 32);
    bf16x8 ql0 = ldfrag(Ql + qbase), ql1 = ldfrag(Ql + qbase + 32);

    float mrun = -1e30f, lrun = 0.f;  // per-lane; lrun = partial over this lane's keys
    f32x4 oacc[4];
#pragma unroll
    for (int d = 0; d < 4; d++) oacc[d] = {0.f, 0.f, 0.f, 0.f};

    const int nkt0 = (vl[n] + 31) >> 5;
    const int nkt1 = (vl[4 + n] + 31) >> 5;
    const int mykt = s ? nkt1 : nkt0;
    const int nktmax = nkt0 > nkt1 ? nkt0 : nkt1;

    // staging: 24 x 1KB chunks per kt, 3 per wave
    const u16* gsrc[3];
    u16* ldst[3];
    int ginc[3], lstr[3];
#pragma unroll
    for (int i = 0; i < 3; i++) {
        const int c  = w * 3 + i;
        const int cs = c / 12, cr = c % 12;
        if (cr < 8) {
            const int hl = cr >> 2, rr = cr & 3;
            const u16* K = ws + OFF_QKV + (size_t)(2 + cs * 4 + hl) * E;
            gsrc[i] = K + (nh * L + rr * 8 + (lane >> 3)) * DH + (lane & 7) * 8;
            ldst[i] = &kbuf[0][cs][hl][rr * 8][0];
            ginc[i] = 32 * DH;
            lstr[i] = 2 * 2 * 32 * 64;
        } else {
            const int rr = cr - 8;
            const u16* V = ws + OFF_QKV + (size_t)(8 + cs) * E;
            gsrc[i] = V + (nh * DH + rr * 16 + (lane >> 2)) * L + (lane & 3) * 8;
            ldst[i] = &vbuf[0][cs][rr * 16][0];
            ginc[i] = 32;
            lstr[i] = 2 * 64 * 32;
        }
    }

    // prologue: stage tile 0 into buffer 0
#pragma unroll
    for (int i = 0; i < 3; i++) { gld16(gsrc[i], ldst[i]); gsrc[i] += ginc[i]; }
    __syncthreads();

    int cur = 0;
    const int srcb = (lane & 48) + ((lane >> 4) << 2);  // lane with lr = own row g*4 (+r)

#pragma unroll 1
    for (int kt = 0; kt < nktmax; kt++) {
        if (kt + 1 < nktmax) {
            const int nb = cur ^ 1;
#pragma unroll
            for (int i = 0; i < 3; i++) { gld16(gsrc[i], ldst[i] + nb * lstr[i]); gsrc[i] += ginc[i]; }
        }

        if (kt < mykt) {
            // --- QK^T swapped: lane holds S[key = j*16+g*4+r][query = lr] ---
            __builtin_amdgcn_s_setprio(1);
            f32x4 sfr[2];
#pragma unroll
            for (int j = 0; j < 2; j++) {
                const int row = j * 16 + lr;
                const int t0 = g ^ (row & 7);
                const int t1 = (g + 4) ^ (row & 7);
                bf16x8 kh0 = ldfrag(&kbuf[cur][s][0][row][t0 * 8]);
                bf16x8 kh1 = ldfrag(&kbuf[cur][s][0][row][t1 * 8]);
                bf16x8 kl0 = ldfrag(&kbuf[cur][s][1][row][t0 * 8]);
                bf16x8 kl1 = ldfrag(&kbuf[cur][s][1][row][t1 * 8]);
                f32x4 a = {0.f, 0.f, 0.f, 0.f};
                a = __builtin_amdgcn_mfma_f32_16x16x32_bf16(kh0, qh0, a, 0, 0, 0);
                a = __builtin_amdgcn_mfma_f32_16x16x32_bf16(kh1, qh1, a, 0, 0, 0);
                a = __builtin_amdgcn_mfma_f32_16x16x32_bf16(kl0, qh0, a, 0, 0, 0);
                a = __builtin_amdgcn_mfma_f32_16x16x32_bf16(kl1, qh1, a, 0, 0, 0);
                a = __builtin_amdgcn_mfma_f32_16x16x32_bf16(kh0, ql0, a, 0, 0, 0);
                a = __builtin_amdgcn_mfma_f32_16x16x32_bf16(kh1, ql1, a, 0, 0, 0);
                sfr[j] = a;
            }
            __builtin_amdgcn_s_setprio(0);
            // --- lane-local online softmax in exp2 domain ---
            const int kb0 = kt * 32 + g * 4;
            float tm = -1e30f;
#pragma unroll
            for (int j = 0; j < 2; j++)
#pragma unroll
                for (int r = 0; r < 4; r++) {
                    float sv = (kb0 + j * 16 + r < vls) ? sfr[j][r] : -1e30f;
                    sfr[j][r] = sv;
                    tm = fmaxf(tm, sv);
                }
            tm = fmaxf(tm, __shfl_xor(tm, 16, 64));
            tm = fmaxf(tm, __shfl_xor(tm, 32, 64));
            // defer-max: skip rescale when max growth < 11.5 (exp2 headroom 2^11.5)
            if (!__all(tm <= mrun + 11.5f)) {
                float mnew = fmaxf(mrun, tm);
                float sc = __builtin_amdgcn_exp2f(mrun - mnew);
                mrun = mnew;
                lrun *= sc;
                float scq0 = __shfl(sc, srcb + 0, 64), scq1 = __shfl(sc, srcb + 1, 64);
                float scq2 = __shfl(sc, srcb + 2, 64), scq3 = __shfl(sc, srcb + 3, 64);
#pragma unroll
                for (int d = 0; d < 4; d++) {
                    oacc[d][0] *= scq0; oacc[d][1] *= scq1;
                    oacc[d][2] *= scq2; oacc[d][3] *= scq3;
                }
            }
            float ps = 0.f;
#pragma unroll
            for (int j = 0; j < 2; j++) {
                float e0 = __builtin_amdgcn_exp2f(sfr[j][0] - mrun);
                float e1 = __builtin_amdgcn_exp2f(sfr[j][1] - mrun);
                float e2 = __builtin_amdgcn_exp2f(sfr[j][2] - mrun);
                float e3 = __builtin_amdgcn_exp2f(sfr[j][3] - mrun);
                ps += (e0 + e1) + (e2 + e3);
                unsigned p01 = (unsigned)f2bf(e0) | ((unsigned)f2bf(e1) << 16);
                unsigned p23 = (unsigned)f2bf(e2) | ((unsigned)f2bf(e3) << 16);
                const int kk = j * 16 + g * 4;
                uint2 pk; pk.x = p01; pk.y = p23;
                *reinterpret_cast<uint2*>(&plds[w][lr][kk ^ swz]) = pk;
            }
            lrun += ps;   // partial; g-reduction deferred to epilogue
            // --- P fragment + PV ---
            const int base = (g * 8) ^ swz;
            u16x8v pt = *reinterpret_cast<const u16x8v*>(&plds[w][lr][base]);
            bf16x8 pa = __builtin_bit_cast(bf16x8, pt);
            __builtin_amdgcn_s_setprio(1);
#pragma unroll
            for (int d = 0; d < 4; d++) {
                const int dh = d * 16 + lr;
                const int t = g ^ (dh & 3);
                bf16x8 v8 = ldfrag(&vbuf[cur][s][dh][t * 8]);
                oacc[d] = __builtin_amdgcn_mfma_f32_16x16x32_bf16(pa, v8, oacc[d], 0, 0, 0);
            }
            __builtin_amdgcn_s_setprio(0);
        }
        __syncthreads();   // drains vmcnt: next buffer staged & this buffer free
        cur ^= 1;
    }

    // finalize: complete the deferred lrun reduction across g-groups
    lrun += __shfl_xor(lrun, 16, 64);
    lrun += __shfl_xor(lrun, 32, 64);
    float lq[4];
#pragma unroll
    for (int r = 0; r < 4; r++) lq[r] = __shfl(lrun, srcb + r, 64);
    float ofin[4][4];
#pragma unroll
    for (int r = 0; r < 4; r++) {
        float inv = __builtin_amdgcn_rcpf(lq[r]);
#pragma unroll
        for (int d = 0; d < 4; d++) ofin[d][r] = oacc[d][r] * inv;
    }

    // combine the two key-sources through LDS (reuse kbuf as f32 comb buffer)
    float (*comb)[16][64] = (float(*)[16][64])&kbuf[0][0][0][0][0];
    if (s == 0) {
#pragma unroll
        for (int d = 0; d < 4; d++)
#pragma unroll
            for (int r = 0; r < 4; r++) comb[wq][g * 4 + r][d * 16 + lr] = ofin[d][r];
    }
    __syncthreads();
    if (s == 1) {
        float* ob = out + (size_t)oi * ((size_t)NB * L * D);
#pragma unroll
        for (int r = 0; r < 4; r++) {
            int row = l0 + g * 4 + r;
#pragma unroll
            for (int d = 0; d < 4; d++) {
                float v = 0.5f * (ofin[d][r] + comb[wq][g * 4 + r][d * 16 + lr]);
                v = (row < vlo) ? v : 0.f;
                ob[((size_t)n * L + row) * D + hh * DH + d * 16 + lr] = v;
            }
        }
    }
}

extern "C" void kernel_launch(void* const* d_in, const int* in_sizes, int n_in,
                              void* d_out, int out_size, void* d_ws, size_t ws_size,
                              hipStream_t stream) {
    const float* input1 = (const float*)d_in[0];
    const float* mask1  = (const float*)d_in[1];
    const float* input2 = (const float*)d_in[2];
    const float* mask2  = (const float*)d_in[3];
    u16*   ws  = (u16*)d_ws;
    float* out = (float*)d_out;

    k_split_all<<<5632, 256, 0, stream>>>(input1, input2,
                                          (const float*)d_in[4], (const float*)d_in[5],
                                          (const float*)d_in[6], (const float*)d_in[7],
                                          (const float*)d_in[8], (const float*)d_in[9], ws);
    k_vlen<<<8, 256, 0, stream>>>(mask1, mask2, (int*)(ws + OFF_VLEN));
    k_proj<<<768, 256, 0, stream>>>(ws);
    k_attn<<<1024, 512, 0, stream>>>(ws, out);
}

// Round 8
// 148.363 us; speedup vs baseline: 2.8204x; 1.0451x over previous
//
#include <hip/hip_runtime.h>

#define DEV static __device__ __forceinline__

typedef unsigned short u16;
typedef short bf16x8 __attribute__((ext_vector_type(8)));
typedef u16 u16x8v __attribute__((ext_vector_type(8)));
typedef u16 u16x4v __attribute__((ext_vector_type(4)));
typedef float f32x4 __attribute__((ext_vector_type(4)));

static constexpr int NB = 4, L = 1024, D = 512, H = 8, DH = 64;
static constexpr size_t E  = (size_t)NB * L * D;   // 2,097,152
static constexpr size_t WE = (size_t)D * D;        // 262,144

// d_ws layout in u16 units
// X1/X2/W stored CHUNK-SWIZZLED: element e of row m at e ^ ((m&7)<<3).
static constexpr size_t OFF_X1H = 0;
static constexpr size_t OFF_X1L = OFF_X1H + E;
static constexpr size_t OFF_X2H = OFF_X1L + E;
static constexpr size_t OFF_X2L = OFF_X2H + E;
static constexpr size_t OFF_WH  = OFF_X2L + E;       // 6 x WE
static constexpr size_t OFF_WL  = OFF_WH + 6 * WE;   // 6 x WE
static constexpr size_t OFF_QKV = OFF_WL + 6 * WE;
// OFF_QKV + {0:q1h,1E:q1l,2E:k1h,3E:k1l,4E:q2h,5E:q2l,6E:k2h,7E:k2l,8E:v1t,9E:v2t}
// Q stored PRE-SCALED by log2(e) (softmax runs in exp2 domain).
// K stored dh-SWIZZLED (dh ^= (key&7)<<3)  -> 8 bank positions per quarter-wave.
// V^T stored key-SWIZZLED (key ^= ((dh>>2)&3)<<3 within each 32-key tile) ->
// PV read position spreads over lr bits 2-3 (8 positions incl. bank-half bit).
static constexpr size_t OFF_VLEN = OFF_QKV + 10 * E; // int[8] (s*4+n)

DEV u16 f2bf(float x) {
    unsigned u = __builtin_bit_cast(unsigned, x);
    unsigned r = u + 0x7FFFu + ((u >> 16) & 1u);
    return (u16)(r >> 16);
}
DEV float bf2f(u16 h) {
    unsigned u = ((unsigned)h) << 16;
    return __builtin_bit_cast(float, u);
}
DEV unsigned cvtpk(float lo, float hi) {   // packed f32x2 -> bf16x2 (RNE)
    unsigned r;
    asm("v_cvt_pk_bf16_f32 %0, %1, %2" : "=v"(r) : "v"(lo), "v"(hi));
    return r;
}
DEV bf16x8 ldfrag(const u16* p) {
    u16x8v t = *reinterpret_cast<const u16x8v*>(p);
    return __builtin_bit_cast(bf16x8, t);
}
typedef __attribute__((address_space(1))) const unsigned gas_u32;
typedef __attribute__((address_space(3))) unsigned las_u32;
DEV void gld16(const u16* g, u16* l) {
    __builtin_amdgcn_global_load_lds((gas_u32*)g, (las_u32*)l, 16, 0, 0);
}

// ---------------- fused split fp32 -> (hi, lo) bf16, chunk-swizzled ----------------
__global__ __launch_bounds__(256) void k_split_all(const float* __restrict__ x1,
                                                   const float* __restrict__ x2,
                                                   const float* w0, const float* w1,
                                                   const float* w2, const float* w3,
                                                   const float* w4, const float* w5,
                                                   u16* __restrict__ ws) {
    int b = blockIdx.x;
    const float* src;
    u16 *hi, *lo;
    int i0;
    if (b < 2048)      { src = x1; hi = ws + OFF_X1H; lo = ws + OFF_X1L; i0 = b; }
    else if (b < 4096) { src = x2; hi = ws + OFF_X2H; lo = ws + OFF_X2L; i0 = b - 2048; }
    else {
        int wi = (b - 4096) >> 8;
        const float* wp[6] = {w0, w1, w2, w3, w4, w5};
        src = wp[wi];
        hi = ws + OFF_WH + (size_t)wi * WE;
        lo = ws + OFF_WL + (size_t)wi * WE;
        i0 = (b - 4096) & 255;
    }
    int i = i0 * 256 + threadIdx.x;
    float4 v = reinterpret_cast<const float4*>(src)[i];
    float xs[4] = {v.x, v.y, v.z, v.w};
    u16x4v h, l;
#pragma unroll
    for (int j = 0; j < 4; j++) {
        u16 hh = f2bf(xs[j]);
        h[j] = hh;
        l[j] = f2bf(xs[j] - bf2f(hh));
    }
    // chunk-swizzle: idx = m*512 + e ; store at m*512 + (e ^ ((m&7)<<3))
    int idx = i * 4;
    int m = idx >> 9, e = idx & 511;
    int o = (m << 9) | (e ^ ((m & 7) << 3));
    *reinterpret_cast<u16x4v*>(hi + o) = h;
    *reinterpret_cast<u16x4v*>(lo + o) = l;
}

// ---------------- valid-length per (src, n): prefix-mask sum ----------------
__global__ __launch_bounds__(256) void k_vlen(const float* __restrict__ m1,
                                              const float* __restrict__ m2,
                                              int* __restrict__ vl) {
    int b = blockIdx.x;            // 0..7 : s*4+n
    int s = b >> 2, n = b & 3;
    const float* m = (s ? m2 : m1) + n * L;
    float p = 0.f;
    for (int i = threadIdx.x; i < L; i += 256) p += m[i];
#pragma unroll
    for (int mk = 1; mk < 64; mk <<= 1) p += __shfl_xor(p, mk, 64);
    __shared__ float w4[4];
    if ((threadIdx.x & 63) == 0) w4[threadIdx.x >> 6] = p;
    __syncthreads();
    if (threadIdx.x == 0) vl[b] = (int)(w4[0] + w4[1] + w4[2] + w4[3] + 0.5f);
}

// ---------------- projections: LDS-staged 128x128 tile, BK=64 ----------------
__global__ __launch_bounds__(256) void k_proj(u16* __restrict__ ws) {
    __shared__ __align__(16) u16 ta[2][128][64];
    __shared__ __align__(16) u16 tb[2][128][64];

    const int b     = blockIdx.x;
    const int proj  = b >> 7;        // 0..5 : q1,k1,v1,q2,k2,v2
    const int rem   = b & 127;
    const int mtile = rem >> 2;
    const int ntile = rem & 3;
    const int tid   = threadIdx.x;
    const int w     = tid >> 6;
    const int lane  = tid & 63;
    const int lr    = lane & 15;
    const int g     = lane >> 4;
    const int wr    = w >> 1, wc = w & 1;

    const int src  = proj / 3;
    const int kind = proj % 3;
    const u16* Xh = ws + (src ? OFF_X2H : OFF_X1H);
    const u16* Xl = ws + (src ? OFF_X2L : OFF_X1L);
    const u16* Wh = ws + OFF_WH + (size_t)proj * WE;
    const u16* Wl = ws + OFF_WL + (size_t)proj * WE;

    const int m0 = mtile * 128, n0 = ntile * 128;

    const int lrow = lane >> 3, lcol = lane & 7;
    const u16* gA0 = Xh + (size_t)(m0 + w * 32 + lrow) * 512 + lcol * 8;
    const u16* gA1 = Xl + (size_t)(m0 + w * 32 + lrow) * 512 + lcol * 8;
    const u16* gB0 = Wh + (size_t)(n0 + w * 32 + lrow) * 512 + lcol * 8;
    const u16* gB1 = Wl + (size_t)(n0 + w * 32 + lrow) * 512 + lcol * 8;

    f32x4 acc[4][4];
#pragma unroll
    for (int fr = 0; fr < 4; fr++)
#pragma unroll
        for (int cb = 0; cb < 4; cb++) acc[fr][cb] = {0.f, 0.f, 0.f, 0.f};

#pragma unroll 1
    for (int step = 0; step < 8; step++) {
        __syncthreads();
#pragma unroll
        for (int i = 0; i < 4; i++) {
            const int roff = w * 32 + i * 8;
            const int e0 = step * 64;
            gld16(gA0 + e0 + i * (8 * 512), &ta[0][roff][0]);
            gld16(gA1 + e0 + i * (8 * 512), &ta[1][roff][0]);
            gld16(gB0 + e0 + i * (8 * 512), &tb[0][roff][0]);
            gld16(gB1 + e0 + i * (8 * 512), &tb[1][roff][0]);
        }
        __syncthreads();

#pragma unroll
        for (int ks = 0; ks < 2; ks++) {
            bf16x8 ah[4], al[4];
#pragma unroll
            for (int fr = 0; fr < 4; fr++) {
                const int row = wr * 64 + fr * 16 + lr;
                const int ch = (ks * 4 + g) ^ (row & 7);
                ah[fr] = ldfrag(&ta[0][row][ch * 8]);
                al[fr] = ldfrag(&ta[1][row][ch * 8]);
            }
#pragma unroll
            for (int cb = 0; cb < 4; cb++) {
                const int rowb = wc * 64 + cb * 16 + lr;
                const int chb = (ks * 4 + g) ^ (rowb & 7);
                bf16x8 bh = ldfrag(&tb[0][rowb][chb * 8]);
                bf16x8 bl = ldfrag(&tb[1][rowb][chb * 8]);
#pragma unroll
                for (int fr = 0; fr < 4; fr++) {
                    acc[fr][cb] = __builtin_amdgcn_mfma_f32_16x16x32_bf16(ah[fr], bh, acc[fr][cb], 0, 0, 0);
                    acc[fr][cb] = __builtin_amdgcn_mfma_f32_16x16x32_bf16(ah[fr], bl, acc[fr][cb], 0, 0, 0);
                    acc[fr][cb] = __builtin_amdgcn_mfma_f32_16x16x32_bf16(al[fr], bh, acc[fr][cb], 0, 0, 0);
                }
            }
        }
    }

    if (kind < 2) {
        const float qscale = (kind == 0) ? 1.4426950408889634f : 1.0f;  // Q in log2 domain
        u16* dhi = ws + OFF_QKV + (size_t)(src * 4 + kind * 2) * E;
        u16* dlo = dhi + E;
#pragma unroll
        for (int fr = 0; fr < 4; fr++)
#pragma unroll
            for (int cb = 0; cb < 4; cb++) {
                int d  = n0 + wc * 64 + cb * 16 + lr;
                int hh = d >> 6, dh = d & 63;
#pragma unroll
                for (int r = 0; r < 4; r++) {
                    int m = m0 + wr * 64 + fr * 16 + g * 4 + r;
                    int n = m >> 10, li = m & 1023;
                    int dhs = kind ? (dh ^ ((li & 7) << 3)) : dh;   // K dh-swizzle
                    size_t idx = ((size_t)(n * H + hh) * L + li) * DH + dhs;
                    float v = acc[fr][cb][r] * qscale;
                    u16 hv = f2bf(v);
                    dhi[idx] = hv;
                    dlo[idx] = f2bf(v - bf2f(hv));
                }
            }
    } else {
        u16* vt = ws + OFF_QKV + (size_t)(8 + src) * E;
#pragma unroll
        for (int fr = 0; fr < 4; fr++)
#pragma unroll
            for (int cb = 0; cb < 4; cb++) {
                int d  = n0 + wc * 64 + cb * 16 + lr;
                int hh = d >> 6, dh = d & 63;
                int m  = m0 + wr * 64 + fr * 16 + g * 4;
                int n  = m >> 10, li = m & 1023;
                int lis = li ^ (((dh >> 2) & 3) << 3);   // V key-swizzle (bank spread over dh bits 2-3)
                u16x4v pk;
#pragma unroll
                for (int r = 0; r < 4; r++) pk[r] = f2bf(acc[fr][cb][r]);
                *reinterpret_cast<u16x4v*>(vt + ((size_t)(n * H + hh) * DH + dh) * L + lis) = pk;
            }
    }
}

// ---------------- fused two-source flash attention, KVBLK=32 ----------------
// grid 1024 blocks x 512 thr; block=(oi,n,h,qt), wave=(s, wq); 16 q-rows/wave.
// 56KB LDS -> 2 blocks/CU. Double-buffered K/V, swapped-QK lane-local softmax
// in exp2 domain, defer-max rescale skip, setprio, cvt_pk P conversion.
__global__ __launch_bounds__(512, 4) void k_attn(const u16* __restrict__ ws,
                                                 float* __restrict__ out) {
    __shared__ __align__(16) u16 kbuf[2][2][2][32][64]; // [dbuf][src][hi/lo][key][dh-swz] 32KB
    __shared__ __align__(16) u16 vbuf[2][2][64][32];    // [dbuf][src][dh][key-swz]        16KB
    __shared__ __align__(16) u16 plds[8][16][32];       // per-wave P [query][key-swz]      8KB

    const int bid  = blockIdx.x;
    const int b    = ((bid & 7) << 7) | (bid >> 3);  // XCD-contiguous qt runs
    const int oi   = b >> 9;
    const int rem  = b & 511;
    const int qt   = rem & 15;
    const int hh   = (rem >> 4) & 7;
    const int n    = rem >> 7;
    const int tid  = threadIdx.x;
    const int w    = tid >> 6;
    const int s    = w >> 2;        // key source
    const int wq   = w & 3;         // q sub-tile
    const int lane = tid & 63;
    const int lr   = lane & 15;
    const int g    = lane >> 4;
    const int swz  = ((lr >> 1) & 3) << 3;   // plds swizzle: lr bits 1-2 -> 8 positions/qwave
    const int tsw  = (lr >> 2) & 3;          // vbuf chunk swizzle: lr bits 2-3

    const size_t nh = (size_t)(n * H + hh);
    const u16* Qh = ws + OFF_QKV + (size_t)(oi * 4) * E;
    const u16* Ql = Qh + E;
    const int* vl = (const int*)(ws + OFF_VLEN);
    const int vls = vl[s * 4 + n];    // valid keys for my source
    const int vlo = vl[oi * 4 + n];   // valid rows for my output

    const int l0 = qt * 64 + wq * 16;
    const size_t qbase = (nh * L + l0 + lr) * DH + g * 8;
    bf16x8 qh0 = ldfrag(Qh + qbase), qh1 = ldfrag(Qh + qbase + 32);
    bf16x8 ql0 = ldfrag(Ql + qbase), ql1 = ldfrag(Ql + qbase + 32);

    float mrun = -1e30f, lrun = 0.f;  // per-lane; lrun partial over this lane's keys
    f32x4 oacc[4];
#pragma unroll
    for (int d = 0; d < 4; d++) oacc[d] = {0.f, 0.f, 0.f, 0.f};

    const int nkt0 = (vl[n] + 31) >> 5;
    const int nkt1 = (vl[4 + n] + 31) >> 5;
    const int mykt = s ? nkt1 : nkt0;
    const int nktmax = nkt0 > nkt1 ? nkt0 : nkt1;

    // staging: 24 x 1KB chunks per kt, 3 per wave
    const u16* gsrc[3];
    u16* ldst[3];
    int ginc[3], lstr[3];
#pragma unroll
    for (int i = 0; i < 3; i++) {
        const int c  = w * 3 + i;
        const int cs = c / 12, cr = c % 12;
        if (cr < 8) {
            const int hl = cr >> 2, rr = cr & 3;
            const u16* K = ws + OFF_QKV + (size_t)(2 + cs * 4 + hl) * E;
            gsrc[i] = K + (nh * L + rr * 8 + (lane >> 3)) * DH + (lane & 7) * 8;
            ldst[i] = &kbuf[0][cs][hl][rr * 8][0];
            ginc[i] = 32 * DH;
            lstr[i] = 2 * 2 * 32 * 64;
        } else {
            const int rr = cr - 8;
            const u16* V = ws + OFF_QKV + (size_t)(8 + cs) * E;
            gsrc[i] = V + (nh * DH + rr * 16 + (lane >> 2)) * L + (lane & 3) * 8;
            ldst[i] = &vbuf[0][cs][rr * 16][0];
            ginc[i] = 32;
            lstr[i] = 2 * 64 * 32;
        }
    }

    // prologue: stage tile 0 into buffer 0
#pragma unroll
    for (int i = 0; i < 3; i++) { gld16(gsrc[i], ldst[i]); gsrc[i] += ginc[i]; }
    __syncthreads();

    int cur = 0;
    const int srcb = (lane & 48) + ((lane >> 4) << 2);  // lane with lr = own row g*4 (+r)

#pragma unroll 1
    for (int kt = 0; kt < nktmax; kt++) {
        if (kt + 1 < nktmax) {
            const int nb = cur ^ 1;
#pragma unroll
            for (int i = 0; i < 3; i++) { gld16(gsrc[i], ldst[i] + nb * lstr[i]); gsrc[i] += ginc[i]; }
        }

        if (kt < mykt) {
            // --- QK^T swapped: lane holds S[key = j*16+g*4+r][query = lr] ---
            __builtin_amdgcn_s_setprio(1);
            f32x4 sfr[2];
#pragma unroll
            for (int j = 0; j < 2; j++) {
                const int row = j * 16 + lr;
                const int t0 = g ^ (row & 7);
                const int t1 = (g + 4) ^ (row & 7);
                bf16x8 kh0 = ldfrag(&kbuf[cur][s][0][row][t0 * 8]);
                bf16x8 kh1 = ldfrag(&kbuf[cur][s][0][row][t1 * 8]);
                bf16x8 kl0 = ldfrag(&kbuf[cur][s][1][row][t0 * 8]);
                bf16x8 kl1 = ldfrag(&kbuf[cur][s][1][row][t1 * 8]);
                f32x4 a = {0.f, 0.f, 0.f, 0.f};
                a = __builtin_amdgcn_mfma_f32_16x16x32_bf16(kh0, qh0, a, 0, 0, 0);
                a = __builtin_amdgcn_mfma_f32_16x16x32_bf16(kh1, qh1, a, 0, 0, 0);
                a = __builtin_amdgcn_mfma_f32_16x16x32_bf16(kl0, qh0, a, 0, 0, 0);
                a = __builtin_amdgcn_mfma_f32_16x16x32_bf16(kl1, qh1, a, 0, 0, 0);
                a = __builtin_amdgcn_mfma_f32_16x16x32_bf16(kh0, ql0, a, 0, 0, 0);
                a = __builtin_amdgcn_mfma_f32_16x16x32_bf16(kh1, ql1, a, 0, 0, 0);
                sfr[j] = a;
            }
            __builtin_amdgcn_s_setprio(0);
            // --- lane-local online softmax in exp2 domain ---
            // mask clamp only on the (single) partial tile (wave-uniform branch)
            if ((kt << 5) + 32 > vls) {
                const int kb0 = (kt << 5) + g * 4;
#pragma unroll
                for (int j = 0; j < 2; j++)
#pragma unroll
                    for (int r = 0; r < 4; r++)
                        if (kb0 + j * 16 + r >= vls) sfr[j][r] = -1e30f;
            }
            float tm = fmaxf(fmaxf(fmaxf(sfr[0][0], sfr[0][1]), fmaxf(sfr[0][2], sfr[0][3])),
                             fmaxf(fmaxf(sfr[1][0], sfr[1][1]), fmaxf(sfr[1][2], sfr[1][3])));
            tm = fmaxf(tm, __shfl_xor(tm, 16, 64));
            tm = fmaxf(tm, __shfl_xor(tm, 32, 64));
            // defer-max: skip rescale when max growth < 11.5 (exp2 headroom 2^11.5)
            if (!__all(tm <= mrun + 11.5f)) {
                float mnew = fmaxf(mrun, tm);
                float sc = __builtin_amdgcn_exp2f(mrun - mnew);
                mrun = mnew;
                lrun *= sc;
                float scq0 = __shfl(sc, srcb + 0, 64), scq1 = __shfl(sc, srcb + 1, 64);
                float scq2 = __shfl(sc, srcb + 2, 64), scq3 = __shfl(sc, srcb + 3, 64);
#pragma unroll
                for (int d = 0; d < 4; d++) {
                    oacc[d][0] *= scq0; oacc[d][1] *= scq1;
                    oacc[d][2] *= scq2; oacc[d][3] *= scq3;
                }
            }
            float ps = 0.f;
#pragma unroll
            for (int j = 0; j < 2; j++) {
                float e0 = __builtin_amdgcn_exp2f(sfr[j][0] - mrun);
                float e1 = __builtin_amdgcn_exp2f(sfr[j][1] - mrun);
                float e2 = __builtin_amdgcn_exp2f(sfr[j][2] - mrun);
                float e3 = __builtin_amdgcn_exp2f(sfr[j][3] - mrun);
                ps += (e0 + e1) + (e2 + e3);
                uint2 pk;
                pk.x = cvtpk(e0, e1);
                pk.y = cvtpk(e2, e3);
                *reinterpret_cast<uint2*>(&plds[w][lr][(j * 16 + g * 4) ^ swz]) = pk;
            }
            lrun += ps;   // partial; g-reduction deferred to epilogue
            // --- P fragment + PV ---
            const int base = (g * 8) ^ swz;
            u16x8v pt = *reinterpret_cast<const u16x8v*>(&plds[w][lr][base]);
            bf16x8 pa = __builtin_bit_cast(bf16x8, pt);
            const int t = g ^ tsw;   // V chunk (same for all d)
            __builtin_amdgcn_s_setprio(1);
#pragma unroll
            for (int d = 0; d < 4; d++) {
                const int dh = d * 16 + lr;
                bf16x8 v8 = ldfrag(&vbuf[cur][s][dh][t * 8]);
                oacc[d] = __builtin_amdgcn_mfma_f32_16x16x32_bf16(pa, v8, oacc[d], 0, 0, 0);
            }
            __builtin_amdgcn_s_setprio(0);
        }
        __syncthreads();   // drains vmcnt: next buffer staged & this buffer free
        cur ^= 1;
    }

    // finalize: complete the deferred lrun reduction across g-groups
    lrun += __shfl_xor(lrun, 16, 64);
    lrun += __shfl_xor(lrun, 32, 64);
    float lq[4];
#pragma unroll
    for (int r = 0; r < 4; r++) lq[r] = __shfl(lrun, srcb + r, 64);
    float ofin[4][4];
#pragma unroll
    for (int r = 0; r < 4; r++) {
        float inv = __builtin_amdgcn_rcpf(lq[r]);
#pragma unroll
        for (int d = 0; d < 4; d++) ofin[d][r] = oacc[d][r] * inv;
    }

    // combine the two key-sources through LDS (reuse kbuf as f32 comb buffer)
    float (*comb)[16][64] = (float(*)[16][64])&kbuf[0][0][0][0][0];
    if (s == 0) {
#pragma unroll
        for (int d = 0; d < 4; d++)
#pragma unroll
            for (int r = 0; r < 4; r++) comb[wq][g * 4 + r][d * 16 + lr] = ofin[d][r];
    }
    __syncthreads();
    if (s == 1) {
        float* ob = out + (size_t)oi * ((size_t)NB * L * D);
#pragma unroll
        for (int r = 0; r < 4; r++) {
            int row = l0 + g * 4 + r;
#pragma unroll
            for (int d = 0; d < 4; d++) {
                float v = 0.5f * (ofin[d][r] + comb[wq][g * 4 + r][d * 16 + lr]);
                v = (row < vlo) ? v : 0.f;
                ob[((size_t)n * L + row) * D + hh * DH + d * 16 + lr] = v;
            }
        }
    }
}

extern "C" void kernel_launch(void* const* d_in, const int* in_sizes, int n_in,
                              void* d_out, int out_size, void* d_ws, size_t ws_size,
                              hipStream_t stream) {
    const float* input1 = (const float*)d_in[0];
    const float* mask1  = (const float*)d_in[1];
    const float* input2 = (const float*)d_in[2];
    const float* mask2  = (const float*)d_in[3];
    u16*   ws  = (u16*)d_ws;
    float* out = (float*)d_out;

    k_split_all<<<5632, 256, 0, stream>>>(input1, input2,
                                          (const float*)d_in[4], (const float*)d_in[5],
                                          (const float*)d_in[6], (const float*)d_in[7],
                                          (const float*)d_in[8], (const float*)d_in[9], ws);
    k_vlen<<<8, 256, 0, stream>>>(mask1, mask2, (int*)(ws + OFF_VLEN));
    k_proj<<<768, 256, 0, stream>>>(ws);
    k_attn<<<1024, 512, 0, stream>>>(ws, out);
}